// Round 17
// baseline (241.974 us; speedup 1.0000x reference)
//
#include <hip/hip_runtime.h>
#include <stdint.h>

typedef unsigned short u16;
typedef __attribute__((ext_vector_type(8))) short bf16x8;   // 8 bf16 = 4 VGPRs
typedef __attribute__((ext_vector_type(4))) float f32x4;

#define NUM_B 2
#define SEQ   2048
#define SEQP  2080      // padded V row stride
#define NH    16
#define HD    128
#define EMB   2048      // NH*HD
#define N3    6144      // 3*EMB
#define MM    4096      // NUM_B*SEQ
#define QT    256       // flash q-rows per block (8 waves)
#define WQ    32        // flash q-rows per wave
#define KT    64        // flash keys per k-tile
#define NTILE (SEQ / KT)

// ---- GEMM tile params: 128x128, BK=64, 4 waves, 64 KB LDS -> 2 blocks/CU ----
#define BM 128
#define BN 128
#define BK 64
#define NT_K (EMB / BK)   // 32 K-tiles

__device__ __forceinline__ u16 f2bf(float f) {
  union { float f; unsigned u; } c; c.f = f;
  return (u16)((c.u + 0x7FFFu + ((c.u >> 16) & 1u)) >> 16);   // RNE
}
__device__ __forceinline__ void async16(const void* g, void* l) {
  __builtin_amdgcn_global_load_lds(
      (const __attribute__((address_space(1))) void*)g,
      (__attribute__((address_space(3))) void*)l, 16, 0, 0);
}

#define GBAR()   asm volatile("s_barrier" ::: "memory")
#define WVM0()   asm volatile("s_waitcnt vmcnt(0)" ::: "memory")

// ---------------- prep: fused bf16-cast (+sincos table) and W-transpose ----------------
#define CVT_BLKS (MM * EMB / 4 / 256)          // 8192
#define TRN_BX   (N3 / 32)                     // 192
__global__ void k_prep(const float* __restrict__ x, u16* __restrict__ xb,
                       float2* __restrict__ tab,
                       const float* __restrict__ W, u16* __restrict__ Wt) {
  __shared__ float t[32][33];
  const int bid = blockIdx.x;
  if (bid < CVT_BLKS) {
    int i = bid * 256 + threadIdx.x;
    const float4 v = ((const float4*)x)[i];
    ushort4 o;
    o.x = f2bf(v.x); o.y = f2bf(v.y); o.z = f2bf(v.z); o.w = f2bf(v.w);
    ((ushort4*)xb)[i] = o;
    if (i < SEQ * HD) {
      double tt = (double)i;
      tab[i] = make_float2((float)cos(tt), (float)sin(tt));
    }
  } else {
    int b2 = bid - CVT_BLKS;
    int n0 = (b2 % TRN_BX) * 32, k0 = (b2 / TRN_BX) * 32;
    int tx = threadIdx.x & 31, ty = threadIdx.x >> 5;   // 32 x 8
    #pragma unroll
    for (int i = ty; i < 32; i += 8)
      t[i][tx] = W[(size_t)(k0 + i) * N3 + n0 + tx];
    __syncthreads();
    #pragma unroll
    for (int i = ty; i < 32; i += 8)
      Wt[(size_t)(n0 + i) * EMB + k0 + tx] = f2bf(t[tx][i]);
  }
}

// ---------------- QKV GEMM: 128x128, 4 waves, 2 blocks/CU (m97-structure port) ----------------
// R16 post-mortem: all 1-block/CU schedules (R4/R8/R12) cap at ~42% resident
// because barrier+vmcnt stalls have no co-resident block to hide under.
// m97/m103 (guide): 128x128 / 4 waves / small LDS -> 2-3 blocks/CU, naive
// 2-barrier loop, 874-912 TF (35-37%) -- the cross-BLOCK overlap (m114) does
// the pipelining. This port: BK=64, LDS lsA[2]+lsB[2] = 64 KB -> 2 blocks/CU
// (16 waves/CU incl. both blocks); acc[4][4]=64 AGPR + ~90 VGPR fits
// 2 waves/SIMD. Grid 48x32 = 1536 blocks = EXACTLY 3.0 rounds at 2/CU.
// Loop (R10-shape, proven safe): WVM0 (own stage(t) landed); GBAR (all waves'
// stage(t) landed + buf[1-p] reads from t-1 complete); stage(t+1)->buf[1-p];
// compute buf[p]. Prefetch distance = one tile compute (~1242 cyc/SIMD) and
// the co-resident block fills the residual drain.
// Swizzle (T2, 0-conflict R1-R16): slot quad = quad ^ (row&7) on per-lane
// GLOBAL source (LDS dest linear) + on ds_read quad; qsw[kk]=((kk*4+lr)^(lq&7))*8.
// N-mapping (1 head per 128-col tile, H = blockIdx.x): wave wc (0,1), pair
// pl (0,1), nf = 2*pl+half -> col = half*64 + wc*32 + pl*16 + lq. Each wave
// holds both halves of its 2 RoPE pairs (d1, d1+64); bijective over 128 cols.
// Accumulation per element: t asc, kk asc -> bit-identical to R12-R16.
__global__ __launch_bounds__(256, 2) void k_gemm_qkv(
    const u16* __restrict__ xb, const u16* __restrict__ wt,
    const float* __restrict__ bias, const float2* __restrict__ tab,
    u16* __restrict__ qb, u16* __restrict__ kb, u16* __restrict__ vbt)
{
  __shared__ __align__(16) u16 lsA[2][BM * BK];   // 16 KB x2
  __shared__ __align__(16) u16 lsB[2][BN * BK];   // 16 KB x2  (64 KB total)
  const int tid = threadIdx.x;            // 0..255
  const int wave = tid >> 6, lane = tid & 63;
  const int lq = lane & 15, lr = lane >> 4;
  const int wr = wave >> 1, wc = wave & 1;
  const int m0 = blockIdx.y * BM, n0 = blockIdx.x * BN;

  auto stage = [&](int t) {               // whole A+B K-tile: 4+4 loads/thread
    const int kt = t * BK;
    const int buf = t & 1;
    #pragma unroll
    for (int ii = 0; ii < 4; ++ii) {
      int s = ii * 256 + tid;             // 16B slot 0..1023
      int row = s >> 3, gq = (s & 7) ^ (row & 7);
      async16(xb + (size_t)(m0 + row) * EMB + kt + gq * 8, &lsA[buf][s * 8]);
    }
    #pragma unroll
    for (int ii = 0; ii < 4; ++ii) {
      int s = ii * 256 + tid;
      int row = s >> 3, gq = (s & 7) ^ (row & 7);
      async16(wt + (size_t)(n0 + row) * EMB + kt + gq * 8, &lsB[buf][s * 8]);
    }
  };

  f32x4 acc[4][4];
  #pragma unroll
  for (int i = 0; i < 4; ++i)
    #pragma unroll
    for (int j = 0; j < 4; ++j)
      acc[i][j] = f32x4{0.f, 0.f, 0.f, 0.f};

  // per-lane LDS read offsets (u16 units)
  int rbase[4];
  #pragma unroll
  for (int nf = 0; nf < 4; ++nf) {
    int half = nf & 1, pl = nf >> 1;
    int col = half * 64 + wc * 32 + pl * 16 + lq;
    rbase[nf] = col * BK;
  }
  const int aRow0 = (wr * 64 + lq) * BK;
  int qsw[2];
  qsw[0] = ((0 + lr) ^ (lq & 7)) * 8;
  qsw[1] = ((4 + lr) ^ (lq & 7)) * 8;

  // prologue: stage tile 0
  stage(0);

  for (int t = 0; t < NT_K; ++t) {
    const int p = t & 1;
    WVM0();                                // own stage(t) loads landed
    GBAR();                                // all waves' stage(t) landed; buf[1-p] reads (t-1) done
    if (t + 1 < NT_K) stage(t + 1);        // -> buf[1-p]

    const u16* Ap = lsA[p];
    const u16* Bp = lsB[p];

    bf16x8 bfr[4][2];
    #pragma unroll
    for (int nf = 0; nf < 4; ++nf)
      #pragma unroll
      for (int kk = 0; kk < 2; ++kk)
        bfr[nf][kk] = *(const bf16x8*)(Bp + rbase[nf] + qsw[kk]);

    #pragma unroll
    for (int mf = 0; mf < 4; ++mf) {
      bf16x8 afk[2];
      #pragma unroll
      for (int kk = 0; kk < 2; ++kk)
        afk[kk] = *(const bf16x8*)(Ap + aRow0 + (mf * 16) * BK + qsw[kk]);
      #pragma unroll
      for (int kk = 0; kk < 2; ++kk)
        #pragma unroll
        for (int nf = 0; nf < 4; ++nf)
          acc[mf][nf] = __builtin_amdgcn_mfma_f32_16x16x32_bf16(
              afk[kk], bfr[nf][kk], acc[mf][nf], 0, 0, 0);
    }
  }

  // ---------------- epilogue (fused bias + RoPE / V-transpose; 1 head/tile) ----------------
  const int m0w = m0 + wr * 64;
  const int H = blockIdx.x;                // absolute head index (0..47)
  const int w = H >> 4;                    // 0=q, 1=k, 2=v
  const int h = H & 15;
  #pragma unroll
  for (int pl = 0; pl < 2; ++pl) {
    const int d1 = wc * 32 + pl * 16 + lq; // d within head, in [0,64); partner d1+64
    const float b1 = bias[n0 + d1];
    const float b2 = bias[n0 + d1 + 64];

    if (w == 2) {
      // V: transpose to [B,H,D,SEQP], 4 consecutive s per 8B store
      #pragma unroll
      for (int mf = 0; mf < 4; ++mf) {
        int mg0 = m0w + mf * 16 + lr * 4;
        int b = mg0 >> 11, s0 = mg0 & 2047;
        ushort4 pk;
        pk.x = f2bf(acc[mf][2 * pl][0] + b1);
        pk.y = f2bf(acc[mf][2 * pl][1] + b1);
        pk.z = f2bf(acc[mf][2 * pl][2] + b1);
        pk.w = f2bf(acc[mf][2 * pl][3] + b1);
        *(ushort4*)(vbt + ((size_t)(b * NH + h) * HD + d1) * SEQP + s0) = pk;
        pk.x = f2bf(acc[mf][2 * pl + 1][0] + b2);
        pk.y = f2bf(acc[mf][2 * pl + 1][1] + b2);
        pk.z = f2bf(acc[mf][2 * pl + 1][2] + b2);
        pk.w = f2bf(acc[mf][2 * pl + 1][3] + b2);
        *(ushort4*)(vbt + ((size_t)(b * NH + h) * HD + d1 + 64) * SEQP + s0) = pk;
      }
    } else {
      u16* basep = (w == 0) ? qb : kb;
      const float qs = (w == 0) ? 0.12751569843736827f : 1.0f;  // log2(e)/sqrt(128) into q
      #pragma unroll
      for (int mf = 0; mf < 4; ++mf)
        #pragma unroll
        for (int r = 0; r < 4; ++r) {
          int mg = m0w + mf * 16 + lr * 4 + r;
          int b = mg >> 11, s = mg & 2047;
          u16* dst = basep + ((size_t)(b * NH + h) * SEQ + s) * HD;
          float c1 = acc[mf][2 * pl][r]     + b1;
          float c2 = acc[mf][2 * pl + 1][r] + b2;
          float2 s1 = tab[s * HD + d1];
          float2 s2 = tab[s * HD + d1 + 64];
          dst[d1]      = f2bf((c1 * s1.x - c2 * s1.y) * qs);
          dst[d1 + 64] = f2bf((c2 * s2.x + c1 * s2.y) * qs);
        }
    }
  }
}

// ---------------- flash attention: QT=256, KT=64 (R16 form, unchanged) ----------------
__global__ __launch_bounds__(512, 1) void k_flash(
    const u16* __restrict__ qb, const u16* __restrict__ kb,
    const u16* __restrict__ vbt, float* __restrict__ out)
{
  __shared__ __align__(16) u16 lsK[2][KT * HD];   // [key][d]  16 KB x2
  __shared__ __align__(16) u16 lsV[2][HD * KT];   // [d][key]  16 KB x2
  __shared__ __align__(16) u16 lsP[8][WQ * KT];   // per-wave [qrow][key], 4 KB x8

  const int tid = threadIdx.x;            // 0..511
  const int wave = tid >> 6, lane = tid & 63;
  const int lq = lane & 15, lr = lane >> 4;
  const int i = blockIdx.x;               // 0..255
  const int xcd = i & 7, j = i >> 3;      // j: 0..31
  const int bh = xcd * 4 + (j >> 3);      // 4 heads per XCD
  const int q0 = (j & 7) * QT;
  const u16* Qg = qb + ((size_t)bh * SEQ + q0 + wave * WQ) * HD;
  const u16* Kg = kb + (size_t)bh * SEQ * HD;
  const u16* Vg = vbt + (size_t)bh * HD * SEQP;

  auto stage = [&](int tile, int buf) {
    const int k0 = tile * KT;
    #pragma unroll
    for (int ii = 0; ii < 2; ++ii) {
      int c = tid + ii * 512;             // 0..1023 (16 KB K tile)
      int key = c >> 4, grp = c & 15;
      async16(Kg + (size_t)(k0 + key) * HD + ((grp ^ (key & 7)) * 8), lsK[buf] + c * 8);
    }
    #pragma unroll
    for (int ii = 0; ii < 2; ++ii) {
      int c = tid + ii * 512;             // 0..1023 (16 KB V tile)
      int d = c >> 3, g2 = c & 7;
      async16(Vg + (size_t)d * SEQP + k0 + ((g2 ^ ((d >> 1) & 7)) * 8), lsV[buf] + c * 8);
    }
  };

  stage(0, 0);

  bf16x8 qf[2][4];
  #pragma unroll
  for (int qq = 0; qq < 2; ++qq)
    #pragma unroll
    for (int ks = 0; ks < 4; ++ks)
      qf[qq][ks] = *(const bf16x8*)(Qg + (size_t)(qq * 16 + lq) * HD + ks * 32 + lr * 8);

  f32x4 acc_o[2][8];
  float lsum[2] = {0.f, 0.f};
  #pragma unroll
  for (int mb = 0; mb < 2; ++mb)
    #pragma unroll
    for (int nb = 0; nb < 8; ++nb) acc_o[mb][nb] = f32x4{0.f, 0.f, 0.f, 0.f};

  for (int t = 0; t < NTILE; ++t) {
    const int p = t & 1;
    __syncthreads();                 // drains stage(t); all waves done with buf 1-p
    if (t + 1 < NTILE) stage(t + 1, 1 - p);

    // S^T = K Q^T : 64 keys x 32 q-rows per wave
    f32x4 sacc[4][2];
    #pragma unroll
    for (int kbi = 0; kbi < 4; ++kbi)
      #pragma unroll
      for (int qq = 0; qq < 2; ++qq) sacc[kbi][qq] = f32x4{0.f, 0.f, 0.f, 0.f};
    #pragma unroll
    for (int ks = 0; ks < 4; ++ks) {
      bf16x8 kf[4];
      #pragma unroll
      for (int kbi = 0; kbi < 4; ++kbi) {
        int key = kbi * 16 + lq;
        int g = (ks * 4 + lr) ^ (key & 7);
        kf[kbi] = *(const bf16x8*)(lsK[p] + key * HD + g * 8);
      }
      #pragma unroll
      for (int kbi = 0; kbi < 4; ++kbi)
        #pragma unroll
        for (int qq = 0; qq < 2; ++qq)
          sacc[kbi][qq] = __builtin_amdgcn_mfma_f32_16x16x32_bf16(kf[kbi], qf[qq][ks], sacc[kbi][qq], 0, 0, 0);
    }

    // softmax + PV in two key-halves (overlap exp/pack of half 1 with PV of half 0)
    #pragma unroll
    for (int half = 0; half < 2; ++half) {
      // P = exp2(S) for kbi {2*half, 2*half+1}; packed b64 writes
      #pragma unroll
      for (int kb2 = 0; kb2 < 2; ++kb2) {
        int kbi = half * 2 + kb2;
        #pragma unroll
        for (int qq = 0; qq < 2; ++qq) {
          float p0 = __builtin_amdgcn_exp2f(sacc[kbi][qq][0]);
          float p1 = __builtin_amdgcn_exp2f(sacc[kbi][qq][1]);
          float p2 = __builtin_amdgcn_exp2f(sacc[kbi][qq][2]);
          float p3 = __builtin_amdgcn_exp2f(sacc[kbi][qq][3]);
          lsum[qq] += (p0 + p1) + (p2 + p3);
          int row = qq * 16 + lq;
          int g = kbi * 4 + lr;                        // 0..15 (8B groups in 128B row)
          int gp = g ^ (row & 6) ^ ((row & 8) >> 1);
          uint2 pk;
          pk.x = (uint32_t)f2bf(p0) | ((uint32_t)f2bf(p1) << 16);
          pk.y = (uint32_t)f2bf(p2) | ((uint32_t)f2bf(p3) << 16);
          *(uint2*)(lsP[wave] + row * KT + gp * 4) = pk;
        }
      }

      // O += P V for this 32-key slot
      bf16x8 ap[2];
      #pragma unroll
      for (int mb = 0; mb < 2; ++mb) {
        int row = mb * 16 + lq;
        int sw = (row & 6) ^ ((row & 8) >> 1);
        int gb = (half * 8 + 2 * lr) ^ sw;             // even -> 16B-aligned
        ap[mb] = *(const bf16x8*)(lsP[wave] + row * KT + gb * 4);
      }
      #pragma unroll
      for (int nb = 0; nb < 8; ++nb) {
        int d = nb * 16 + lq;
        int q8 = (half * 4 + lr) ^ ((d >> 1) & 7);
        bf16x8 bv = *(const bf16x8*)(lsV[p] + d * KT + q8 * 8);
        #pragma unroll
        for (int mb = 0; mb < 2; ++mb)
          acc_o[mb][nb] = __builtin_amdgcn_mfma_f32_16x16x32_bf16(ap[mb], bv, acc_o[mb][nb], 0, 0, 0);
      }
    }
  }

  float inv[2];
  #pragma unroll
  for (int qq = 0; qq < 2; ++qq) {
    float s = lsum[qq];
    s += __shfl_xor(s, 16);
    s += __shfl_xor(s, 32);
    inv[qq] = 1.0f / s;
  }
  const int b = bh >> 4, h = bh & 15;
  #pragma unroll
  for (int mb = 0; mb < 2; ++mb)
    #pragma unroll
    for (int r = 0; r < 4; ++r) {
      float iv = __shfl(inv[mb], lr * 4 + r);
      int row = wave * WQ + mb * 16 + lr * 4 + r;
      int sq = q0 + row;
      float* op = out + (((size_t)b * SEQ + sq) * NH + h) * HD;
      #pragma unroll
      for (int nb = 0; nb < 8; ++nb)
        op[nb * 16 + lq] = acc_o[mb][nb][r] * iv;
    }
}

// ---------------- launch ----------------

extern "C" void kernel_launch(void* const* d_in, const int* in_sizes, int n_in,
                              void* d_out, int out_size, void* d_ws, size_t ws_size,
                              hipStream_t stream) {
  (void)in_sizes; (void)n_in; (void)out_size; (void)ws_size;
  const float* x    = (const float*)d_in[0];
  const float* W    = (const float*)d_in[1];
  const float* bias = (const float*)d_in[2];
  float* out = (float*)d_out;

  char* p = (char*)d_ws;
  u16* xb  = (u16*)p;  p += (size_t)MM * EMB * 2;                     // 16.8 MB
  u16* wt  = (u16*)p;  p += (size_t)N3 * EMB * 2;                     // 25.2 MB
  u16* qb  = (u16*)p;  p += (size_t)NUM_B * NH * SEQ * HD * 2;        // 16.8 MB
  u16* kb  = (u16*)p;  p += (size_t)NUM_B * NH * SEQ * HD * 2;        // 16.8 MB
  u16* vbt = (u16*)p;  p += (size_t)NUM_B * NH * HD * SEQP * 2;       // 17.0 MB
  float2* tab = (float2*)p;                                           // 2.1 MB

  k_prep<<<CVT_BLKS + TRN_BX * (EMB / 32), 256, 0, stream>>>(x, xb, tab, W, wt);
  k_gemm_qkv<<<dim3(N3 / BN, MM / BM), 256, 0, stream>>>(xb, wt, bias, tab, qb, kb, vbt);
  k_flash<<<SEQ / QT * NUM_B * NH, 512, 0, stream>>>(qb, kb, vbt, out);
}

// Round 19
// 223.398 us; speedup vs baseline: 1.0832x; 1.0832x over previous
//
#include <hip/hip_runtime.h>
#include <stdint.h>

typedef unsigned short u16;
typedef __attribute__((ext_vector_type(8))) short bf16x8;   // 8 bf16 = 4 VGPRs
typedef __attribute__((ext_vector_type(4))) float f32x4;

#define NUM_B 2
#define SEQ   2048
#define SEQP  2080      // padded V row stride
#define NH    16
#define HD    128
#define EMB   2048      // NH*HD
#define N3    6144      // 3*EMB
#define MM    4096      // NUM_B*SEQ
#define QT    256       // flash q-rows per block (8 waves)
#define WQ    32        // flash q-rows per wave
#define KT    64        // flash keys per k-tile
#define NTILE (SEQ / KT)

// ---- GEMM tile params: 128x384, BK=64, 8 waves -> 512 blocks = 2.0 exact rounds ----
// (R12 form, the empirical optimum over 8 probed structures: ~131 us, 32.4%.)
#define BM 128
#define BN 384
#define BK 64
#define NT_K (EMB / BK)   // 32 K-tiles, 16 iterations of 2

__device__ __forceinline__ u16 f2bf(float f) {
  union { float f; unsigned u; } c; c.f = f;
  return (u16)((c.u + 0x7FFFu + ((c.u >> 16) & 1u)) >> 16);   // RNE
}
__device__ __forceinline__ void async16(const void* g, void* l) {
  __builtin_amdgcn_global_load_lds(
      (const __attribute__((address_space(1))) void*)g,
      (__attribute__((address_space(3))) void*)l, 16, 0, 0);
}

#define GBAR()   asm volatile("s_barrier" ::: "memory")
#define WLGKM0() asm volatile("s_waitcnt lgkmcnt(0)" ::: "memory")

// ---------------- prep: fused bf16-cast (+sincos table) and W-transpose ----------------
#define CVT_BLKS (MM * EMB / 4 / 256)          // 8192
#define TRN_BX   (N3 / 32)                     // 192
__global__ void k_prep(const float* __restrict__ x, u16* __restrict__ xb,
                       float2* __restrict__ tab,
                       const float* __restrict__ W, u16* __restrict__ Wt) {
  __shared__ float t[32][33];
  const int bid = blockIdx.x;
  if (bid < CVT_BLKS) {
    int i = bid * 256 + threadIdx.x;
    const float4 v = ((const float4*)x)[i];
    ushort4 o;
    o.x = f2bf(v.x); o.y = f2bf(v.y); o.z = f2bf(v.z); o.w = f2bf(v.w);
    ((ushort4*)xb)[i] = o;
    if (i < SEQ * HD) {
      double tt = (double)i;
      tab[i] = make_float2((float)cos(tt), (float)sin(tt));
    }
  } else {
    int b2 = bid - CVT_BLKS;
    int n0 = (b2 % TRN_BX) * 32, k0 = (b2 / TRN_BX) * 32;
    int tx = threadIdx.x & 31, ty = threadIdx.x >> 5;   // 32 x 8
    #pragma unroll
    for (int i = ty; i < 32; i += 8)
      t[i][tx] = W[(size_t)(k0 + i) * N3 + n0 + tx];
    __syncthreads();
    #pragma unroll
    for (int i = ty; i < 32; i += 8)
      Wt[(size_t)(n0 + i) * EMB + k0 + tx] = f2bf(t[tx][i]);
  }
}

// ---------------- QKV GEMM: 128x384, R4-style schedule, ZERO grid tail ----------------
// (R12 form, verified best: ~131 us, MfmaUtil 32.4, no spill.)
// 8 waves = 2M x 4N -> per-wave 64x96, acc[4][6]=96 AGPR; LDS 128 KB;
// 512 blocks = exactly 2.0 rounds at 1 block/CU. Per tile: Ph0 reads
// bfr[6][2] (12 b128) + af(mf0,1) (4), 24 MFMA; Ph1 reads af(mf2,3) (4),
// 24 MFMA. Staging (buf = t&1): Ph1 stA(t1); Ph2 stB(t0+2,u0,u1)+vmcnt(4);
// Ph3 stA(t0+2)+stB(t0+2,u2); Ph4 stB(t1+2,u0..2)+vmcnt(6). vmcnt ledger in
// R12 notes; never 0 in steady state. Swizzle: quad ^= row&7 on global src +
// ds_read quad (0-conflict R1-R17). N-mapping: pg = 3*wc+pl, head j = pg>>2,
// col = j*128 + (pg&3)*16 + half*64 + lq; q/k/v per group (H = 3*bx + j).
__global__ __launch_bounds__(512, 2) void k_gemm_qkv(
    const u16* __restrict__ xb, const u16* __restrict__ wt,
    const float* __restrict__ bias, const float2* __restrict__ tab,
    u16* __restrict__ qb, u16* __restrict__ kb, u16* __restrict__ vbt)
{
  __shared__ __align__(16) u16 lsA[2][BM * BK];   // 16 KB x2
  __shared__ __align__(16) u16 lsB[2][BN * BK];   // 48 KB x2  (128 KB total)
  const int tid = threadIdx.x;            // 0..511
  const int wave = tid >> 6, lane = tid & 63;
  const int lq = lane & 15, lr = lane >> 4;
  const int wr = wave >> 2, wc = wave & 3;
  const int m0 = blockIdx.y * BM, n0 = blockIdx.x * BN;

  auto stA = [&](int t) {                 // whole 128x64 A tile: 2 loads/thread
    const int kt = t * BK;
    #pragma unroll
    for (int ii = 0; ii < 2; ++ii) {
      int s = ii * 512 + tid;             // 16B slot 0..1023
      int row = s >> 3, gq = (s & 7) ^ (row & 7);
      async16(xb + (size_t)(m0 + row) * EMB + kt + gq * 8, &lsA[t & 1][s * 8]);
    }
  };
  auto stB = [&](int t, int u) {          // one 128-row third: 2 loads/thread
    const int kt = t * BK;
    #pragma unroll
    for (int ii = 0; ii < 2; ++ii) {
      int s = u * 1024 + ii * 512 + tid;  // 16B slot within B tile
      int row = s >> 3, gq = (s & 7) ^ (row & 7);
      async16(wt + (size_t)(n0 + row) * EMB + kt + gq * 8, &lsB[t & 1][s * 8]);
    }
  };

  f32x4 acc[4][6];
  #pragma unroll
  for (int i = 0; i < 4; ++i)
    #pragma unroll
    for (int j = 0; j < 6; ++j)
      acc[i][j] = f32x4{0.f, 0.f, 0.f, 0.f};

  // per-lane LDS read offsets (u16 units)
  int rbase[6];
  #pragma unroll
  for (int nf = 0; nf < 6; ++nf) {
    int pg = 3 * wc + (nf >> 1);
    int col = (pg >> 2) * 128 + (pg & 3) * 16 + (nf & 1) * 64 + lq;
    rbase[nf] = col * BK;
  }
  const int aRow0 = (wr * 64 + lq) * BK;
  int qsw[2];
  qsw[0] = ((0 + lr) ^ (lq & 7)) * 8;
  qsw[1] = ((4 + lr) ^ (lq & 7)) * 8;

  // prologue: A0[2] B0[6] B1[6] = 14 loads; vmcnt(6) -> A0+B0 landed, B1 in flight
  stA(0); stB(0, 0); stB(0, 1); stB(0, 2); stB(1, 0); stB(1, 1); stB(1, 2);
  asm volatile("s_waitcnt vmcnt(6)" ::: "memory");
  GBAR();

  for (int ti = 0; ti < NT_K / 2; ++ti) {
    const int t0 = 2 * ti, t1 = t0 + 1;
    const bool nl = (ti < NT_K / 2 - 1);

    #pragma unroll
    for (int hp = 0; hp < 2; ++hp) {      // hp=0: tile t0 (buf0), hp=1: t1 (buf1)
      const u16* Ap = lsA[hp];
      const u16* Bp = lsB[hp];
      bf16x8 bfr[6][2];

      #pragma unroll
      for (int ph = 0; ph < 2; ++ph) {
        // ---- ds_read register subtile ----
        if (ph == 0) {
          #pragma unroll
          for (int nf = 0; nf < 6; ++nf)
            #pragma unroll
            for (int kk = 0; kk < 2; ++kk)
              bfr[nf][kk] = *(const bf16x8*)(Bp + rbase[nf] + qsw[kk]);
        }
        bf16x8 af[2][2];
        #pragma unroll
        for (int mfl = 0; mfl < 2; ++mfl)
          #pragma unroll
          for (int kk = 0; kk < 2; ++kk)
            af[mfl][kk] = *(const bf16x8*)(Ap + aRow0 + ((ph * 2 + mfl) * 16) * BK + qsw[kk]);

        // ---- stage schedule (R4-mirrored; hazards & vmcnt ledger in R12 notes) ----
        if (hp == 0) {
          if (ph == 0) {
            stA(t1);
          } else {
            if (nl) {
              stB(t0 + 2, 0); stB(t0 + 2, 1);
              asm volatile("s_waitcnt vmcnt(4)" ::: "memory");  // lands B(t1)+A(t1)
            } else {
              asm volatile("s_waitcnt vmcnt(0)" ::: "memory");  // drain for final tile
            }
          }
        } else {
          if (ph == 0) {
            if (nl) { stA(t0 + 2); stB(t0 + 2, 2); }
          } else {
            if (nl) {
              stB(t1 + 2, 0); stB(t1 + 2, 1); stB(t1 + 2, 2);
              asm volatile("s_waitcnt vmcnt(6)" ::: "memory");  // lands tile t0+2
            }
          }
        }
        if (ph == 0) asm volatile("s_waitcnt lgkmcnt(8)" ::: "memory");  // partial drain of 16-read phase

        GBAR();
        WLGKM0();
        __builtin_amdgcn_s_setprio(1);
        #pragma unroll
        for (int kk = 0; kk < 2; ++kk)
          #pragma unroll
          for (int mfl = 0; mfl < 2; ++mfl)
            #pragma unroll
            for (int nf = 0; nf < 6; ++nf)
              acc[ph * 2 + mfl][nf] = __builtin_amdgcn_mfma_f32_16x16x32_bf16(
                  af[mfl][kk], bfr[nf][kk], acc[ph * 2 + mfl][nf], 0, 0, 0);
        __builtin_amdgcn_s_setprio(0);
        GBAR();
      }
    }
  }

  // ---------------- epilogue (fused bias + RoPE / V-transpose, per pair-group) ----------------
  const int m0w = m0 + wr * 64;
  const int bxH = n0 >> 7;                 // = 3 * blockIdx.x
  #pragma unroll
  for (int pl = 0; pl < 3; ++pl) {
    const int pg = 3 * wc + pl;
    const int j = pg >> 2;                 // head within tile (0..2)
    const int s4 = pg & 3;                 // 16-col strip within half-head
    const int H = bxH + j;                 // absolute head index (0..47)
    const int w = H >> 4;                  // 0=q, 1=k, 2=v
    const int h = H & 15;
    const int d1 = s4 * 16 + lq;           // d within head, in [0,64); partner d1+64
    const float b1 = bias[n0 + j * 128 + d1];
    const float b2 = bias[n0 + j * 128 + d1 + 64];

    if (w == 2) {
      // V: transpose to [B,H,D,SEQP], 4 consecutive s per 8B store
      #pragma unroll
      for (int mf = 0; mf < 4; ++mf) {
        int mg0 = m0w + mf * 16 + lr * 4;
        int b = mg0 >> 11, s0 = mg0 & 2047;
        ushort4 pk;
        pk.x = f2bf(acc[mf][2 * pl][0] + b1);
        pk.y = f2bf(acc[mf][2 * pl][1] + b1);
        pk.z = f2bf(acc[mf][2 * pl][2] + b1);
        pk.w = f2bf(acc[mf][2 * pl][3] + b1);
        *(ushort4*)(vbt + ((size_t)(b * NH + h) * HD + d1) * SEQP + s0) = pk;
        pk.x = f2bf(acc[mf][2 * pl + 1][0] + b2);
        pk.y = f2bf(acc[mf][2 * pl + 1][1] + b2);
        pk.z = f2bf(acc[mf][2 * pl + 1][2] + b2);
        pk.w = f2bf(acc[mf][2 * pl + 1][3] + b2);
        *(ushort4*)(vbt + ((size_t)(b * NH + h) * HD + d1 + 64) * SEQP + s0) = pk;
      }
    } else {
      u16* basep = (w == 0) ? qb : kb;
      const float qs = (w == 0) ? 0.12751569843736827f : 1.0f;  // log2(e)/sqrt(128) into q
      #pragma unroll
      for (int mf = 0; mf < 4; ++mf)
        #pragma unroll
        for (int r = 0; r < 4; ++r) {
          int mg = m0w + mf * 16 + lr * 4 + r;
          int b = mg >> 11, s = mg & 2047;
          u16* dst = basep + ((size_t)(b * NH + h) * SEQ + s) * HD;
          float c1 = acc[mf][2 * pl][r]     + b1;
          float c2 = acc[mf][2 * pl + 1][r] + b2;
          float2 s1 = tab[s * HD + d1];
          float2 s2 = tab[s * HD + d1 + 64];
          dst[d1]      = f2bf((c1 * s1.x - c2 * s1.y) * qs);
          dst[d1 + 64] = f2bf((c2 * s2.x + c1 * s2.y) * qs);
        }
    }
  }
}

// ---------------- flash attention: QT=256, KT=64; R16 intra-tile overlap ----------------
// (R16 form, session best: no setprio in lockstep; softmax/PV split into two
// key-halves so half-1's exp/pack runs under half-0's PV MFMAs.
// Bit-identical accumulation order; swizzles <=2-way.)
__global__ __launch_bounds__(512, 1) void k_flash(
    const u16* __restrict__ qb, const u16* __restrict__ kb,
    const u16* __restrict__ vbt, float* __restrict__ out)
{
  __shared__ __align__(16) u16 lsK[2][KT * HD];   // [key][d]  16 KB x2
  __shared__ __align__(16) u16 lsV[2][HD * KT];   // [d][key]  16 KB x2
  __shared__ __align__(16) u16 lsP[8][WQ * KT];   // per-wave [qrow][key], 4 KB x8

  const int tid = threadIdx.x;            // 0..511
  const int wave = tid >> 6, lane = tid & 63;
  const int lq = lane & 15, lr = lane >> 4;
  const int i = blockIdx.x;               // 0..255
  const int xcd = i & 7, j = i >> 3;      // j: 0..31
  const int bh = xcd * 4 + (j >> 3);      // 4 heads per XCD
  const int q0 = (j & 7) * QT;
  const u16* Qg = qb + ((size_t)bh * SEQ + q0 + wave * WQ) * HD;
  const u16* Kg = kb + (size_t)bh * SEQ * HD;
  const u16* Vg = vbt + (size_t)bh * HD * SEQP;

  auto stage = [&](int tile, int buf) {
    const int k0 = tile * KT;
    #pragma unroll
    for (int ii = 0; ii < 2; ++ii) {
      int c = tid + ii * 512;             // 0..1023 (16 KB K tile)
      int key = c >> 4, grp = c & 15;
      async16(Kg + (size_t)(k0 + key) * HD + ((grp ^ (key & 7)) * 8), lsK[buf] + c * 8);
    }
    #pragma unroll
    for (int ii = 0; ii < 2; ++ii) {
      int c = tid + ii * 512;             // 0..1023 (16 KB V tile)
      int d = c >> 3, g2 = c & 7;
      async16(Vg + (size_t)d * SEQP + k0 + ((g2 ^ ((d >> 1) & 7)) * 8), lsV[buf] + c * 8);
    }
  };

  stage(0, 0);

  bf16x8 qf[2][4];
  #pragma unroll
  for (int qq = 0; qq < 2; ++qq)
    #pragma unroll
    for (int ks = 0; ks < 4; ++ks)
      qf[qq][ks] = *(const bf16x8*)(Qg + (size_t)(qq * 16 + lq) * HD + ks * 32 + lr * 8);

  f32x4 acc_o[2][8];
  float lsum[2] = {0.f, 0.f};
  #pragma unroll
  for (int mb = 0; mb < 2; ++mb)
    #pragma unroll
    for (int nb = 0; nb < 8; ++nb) acc_o[mb][nb] = f32x4{0.f, 0.f, 0.f, 0.f};

  for (int t = 0; t < NTILE; ++t) {
    const int p = t & 1;
    __syncthreads();                 // drains stage(t); all waves done with buf 1-p
    if (t + 1 < NTILE) stage(t + 1, 1 - p);

    // S^T = K Q^T : 64 keys x 32 q-rows per wave
    f32x4 sacc[4][2];
    #pragma unroll
    for (int kbi = 0; kbi < 4; ++kbi)
      #pragma unroll
      for (int qq = 0; qq < 2; ++qq) sacc[kbi][qq] = f32x4{0.f, 0.f, 0.f, 0.f};
    #pragma unroll
    for (int ks = 0; ks < 4; ++ks) {
      bf16x8 kf[4];
      #pragma unroll
      for (int kbi = 0; kbi < 4; ++kbi) {
        int key = kbi * 16 + lq;
        int g = (ks * 4 + lr) ^ (key & 7);
        kf[kbi] = *(const bf16x8*)(lsK[p] + key * HD + g * 8);
      }
      #pragma unroll
      for (int kbi = 0; kbi < 4; ++kbi)
        #pragma unroll
        for (int qq = 0; qq < 2; ++qq)
          sacc[kbi][qq] = __builtin_amdgcn_mfma_f32_16x16x32_bf16(kf[kbi], qf[qq][ks], sacc[kbi][qq], 0, 0, 0);
    }

    // softmax + PV in two key-halves (overlap exp/pack of half 1 with PV of half 0)
    #pragma unroll
    for (int half = 0; half < 2; ++half) {
      // P = exp2(S) for kbi {2*half, 2*half+1}; packed b64 writes
      #pragma unroll
      for (int kb2 = 0; kb2 < 2; ++kb2) {
        int kbi = half * 2 + kb2;
        #pragma unroll
        for (int qq = 0; qq < 2; ++qq) {
          float p0 = __builtin_amdgcn_exp2f(sacc[kbi][qq][0]);
          float p1 = __builtin_amdgcn_exp2f(sacc[kbi][qq][1]);
          float p2 = __builtin_amdgcn_exp2f(sacc[kbi][qq][2]);
          float p3 = __builtin_amdgcn_exp2f(sacc[kbi][qq][3]);
          lsum[qq] += (p0 + p1) + (p2 + p3);
          int row = qq * 16 + lq;
          int g = kbi * 4 + lr;                        // 0..15 (8B groups in 128B row)
          int gp = g ^ (row & 6) ^ ((row & 8) >> 1);
          uint2 pk;
          pk.x = (uint32_t)f2bf(p0) | ((uint32_t)f2bf(p1) << 16);
          pk.y = (uint32_t)f2bf(p2) | ((uint32_t)f2bf(p3) << 16);
          *(uint2*)(lsP[wave] + row * KT + gp * 4) = pk;
        }
      }

      // O += P V for this 32-key slot
      bf16x8 ap[2];
      #pragma unroll
      for (int mb = 0; mb < 2; ++mb) {
        int row = mb * 16 + lq;
        int sw = (row & 6) ^ ((row & 8) >> 1);
        int gb = (half * 8 + 2 * lr) ^ sw;             // even -> 16B-aligned
        ap[mb] = *(const bf16x8*)(lsP[wave] + row * KT + gb * 4);
      }
      #pragma unroll
      for (int nb = 0; nb < 8; ++nb) {
        int d = nb * 16 + lq;
        int q8 = (half * 4 + lr) ^ ((d >> 1) & 7);
        bf16x8 bv = *(const bf16x8*)(lsV[p] + d * KT + q8 * 8);
        #pragma unroll
        for (int mb = 0; mb < 2; ++mb)
          acc_o[mb][nb] = __builtin_amdgcn_mfma_f32_16x16x32_bf16(ap[mb], bv, acc_o[mb][nb], 0, 0, 0);
      }
    }
  }

  float inv[2];
  #pragma unroll
  for (int qq = 0; qq < 2; ++qq) {
    float s = lsum[qq];
    s += __shfl_xor(s, 16);
    s += __shfl_xor(s, 32);
    inv[qq] = 1.0f / s;
  }
  const int b = bh >> 4, h = bh & 15;
  #pragma unroll
  for (int mb = 0; mb < 2; ++mb)
    #pragma unroll
    for (int r = 0; r < 4; ++r) {
      float iv = __shfl(inv[mb], lr * 4 + r);
      int row = wave * WQ + mb * 16 + lr * 4 + r;
      int sq = q0 + row;
      float* op = out + (((size_t)b * SEQ + sq) * NH + h) * HD;
      #pragma unroll
      for (int nb = 0; nb < 8; ++nb)
        op[nb * 16 + lq] = acc_o[mb][nb][r] * iv;
    }
}

// ---------------- launch ----------------

extern "C" void kernel_launch(void* const* d_in, const int* in_sizes, int n_in,
                              void* d_out, int out_size, void* d_ws, size_t ws_size,
                              hipStream_t stream) {
  (void)in_sizes; (void)n_in; (void)out_size; (void)ws_size;
  const float* x    = (const float*)d_in[0];
  const float* W    = (const float*)d_in[1];
  const float* bias = (const float*)d_in[2];
  float* out = (float*)d_out;

  char* p = (char*)d_ws;
  u16* xb  = (u16*)p;  p += (size_t)MM * EMB * 2;                     // 16.8 MB
  u16* wt  = (u16*)p;  p += (size_t)N3 * EMB * 2;                     // 25.2 MB
  u16* qb  = (u16*)p;  p += (size_t)NUM_B * NH * SEQ * HD * 2;        // 16.8 MB
  u16* kb  = (u16*)p;  p += (size_t)NUM_B * NH * SEQ * HD * 2;        // 16.8 MB
  u16* vbt = (u16*)p;  p += (size_t)NUM_B * NH * HD * SEQP * 2;       // 17.0 MB
  float2* tab = (float2*)p;                                           // 2.1 MB

  k_prep<<<CVT_BLKS + TRN_BX * (EMB / 32), 256, 0, stream>>>(x, xb, tab, W, wt);
  k_gemm_qkv<<<dim3(N3 / BN, MM / BM), 512, 0, stream>>>(xb, wt, bias, tab, qb, kb, vbt);
  k_flash<<<SEQ / QT * NUM_B * NH, 512, 0, stream>>>(qb, kb, vbt, out);
}

// Round 20
// 220.197 us; speedup vs baseline: 1.0989x; 1.0145x over previous
//
#include <hip/hip_runtime.h>
#include <stdint.h>

typedef unsigned short u16;
typedef __attribute__((ext_vector_type(8))) short bf16x8;   // 8 bf16 = 4 VGPRs
typedef __attribute__((ext_vector_type(4))) float f32x4;

#define NUM_B 2
#define SEQ   2048
#define SEQP  2080      // padded V row stride
#define NH    16
#define HD    128
#define EMB   2048      // NH*HD
#define N3    6144      // 3*EMB
#define MM    4096      // NUM_B*SEQ
#define QT    256       // flash q-rows per block (8 waves)
#define WQ    32        // flash q-rows per wave
#define KT    64        // flash keys per k-tile
#define NTILE (SEQ / KT)

// ---- GEMM tile params: 128x384, BK=64, 8 waves -> 512 blocks = 2.0 exact rounds ----
// (R12 form, the empirical optimum over 8 probed structures: ~131 us, 32.4%.)
#define BM 128
#define BN 384
#define BK 64
#define NT_K (EMB / BK)   // 32 K-tiles, 16 iterations of 2

__device__ __forceinline__ u16 f2bf(float f) {
  union { float f; unsigned u; } c; c.f = f;
  return (u16)((c.u + 0x7FFFu + ((c.u >> 16) & 1u)) >> 16);   // RNE
}
__device__ __forceinline__ void async16(const void* g, void* l) {
  __builtin_amdgcn_global_load_lds(
      (const __attribute__((address_space(1))) void*)g,
      (__attribute__((address_space(3))) void*)l, 16, 0, 0);
}
// HW packed f32->bf16 (RNE; bit-identical to f2bf for finite inputs).
// T12 recipe: no builtin on gfx950, inline asm is the supported form.
__device__ __forceinline__ uint32_t cvtpk_bf16(float lo, float hi) {
  uint32_t r;
  asm("v_cvt_pk_bf16_f32 %0, %1, %2" : "=v"(r) : "v"(lo), "v"(hi));
  return r;
}

#define GBAR()   asm volatile("s_barrier" ::: "memory")
#define WLGKM0() asm volatile("s_waitcnt lgkmcnt(0)" ::: "memory")

// ---------------- prep: fused bf16-cast (+sincos table) and W-transpose ----------------
#define CVT_BLKS (MM * EMB / 4 / 256)          // 8192
#define TRN_BX   (N3 / 32)                     // 192
__global__ void k_prep(const float* __restrict__ x, u16* __restrict__ xb,
                       float2* __restrict__ tab,
                       const float* __restrict__ W, u16* __restrict__ Wt) {
  __shared__ float t[32][33];
  const int bid = blockIdx.x;
  if (bid < CVT_BLKS) {
    int i = bid * 256 + threadIdx.x;
    const float4 v = ((const float4*)x)[i];
    ushort4 o;
    o.x = f2bf(v.x); o.y = f2bf(v.y); o.z = f2bf(v.z); o.w = f2bf(v.w);
    ((ushort4*)xb)[i] = o;
    if (i < SEQ * HD) {
      double tt = (double)i;
      tab[i] = make_float2((float)cos(tt), (float)sin(tt));
    }
  } else {
    int b2 = bid - CVT_BLKS;
    int n0 = (b2 % TRN_BX) * 32, k0 = (b2 / TRN_BX) * 32;
    int tx = threadIdx.x & 31, ty = threadIdx.x >> 5;   // 32 x 8
    #pragma unroll
    for (int i = ty; i < 32; i += 8)
      t[i][tx] = W[(size_t)(k0 + i) * N3 + n0 + tx];
    __syncthreads();
    #pragma unroll
    for (int i = ty; i < 32; i += 8)
      Wt[(size_t)(n0 + i) * EMB + k0 + tx] = f2bf(t[tx][i]);
  }
}

// ---------------- QKV GEMM: 128x384, R4-style schedule, ZERO grid tail ----------------
// (R12 form, verified best: ~131 us, MfmaUtil 32.4, no spill. UNCHANGED.)
__global__ __launch_bounds__(512, 2) void k_gemm_qkv(
    const u16* __restrict__ xb, const u16* __restrict__ wt,
    const float* __restrict__ bias, const float2* __restrict__ tab,
    u16* __restrict__ qb, u16* __restrict__ kb, u16* __restrict__ vbt)
{
  __shared__ __align__(16) u16 lsA[2][BM * BK];   // 16 KB x2
  __shared__ __align__(16) u16 lsB[2][BN * BK];   // 48 KB x2  (128 KB total)
  const int tid = threadIdx.x;            // 0..511
  const int wave = tid >> 6, lane = tid & 63;
  const int lq = lane & 15, lr = lane >> 4;
  const int wr = wave >> 2, wc = wave & 3;
  const int m0 = blockIdx.y * BM, n0 = blockIdx.x * BN;

  auto stA = [&](int t) {                 // whole 128x64 A tile: 2 loads/thread
    const int kt = t * BK;
    #pragma unroll
    for (int ii = 0; ii < 2; ++ii) {
      int s = ii * 512 + tid;             // 16B slot 0..1023
      int row = s >> 3, gq = (s & 7) ^ (row & 7);
      async16(xb + (size_t)(m0 + row) * EMB + kt + gq * 8, &lsA[t & 1][s * 8]);
    }
  };
  auto stB = [&](int t, int u) {          // one 128-row third: 2 loads/thread
    const int kt = t * BK;
    #pragma unroll
    for (int ii = 0; ii < 2; ++ii) {
      int s = u * 1024 + ii * 512 + tid;  // 16B slot within B tile
      int row = s >> 3, gq = (s & 7) ^ (row & 7);
      async16(wt + (size_t)(n0 + row) * EMB + kt + gq * 8, &lsB[t & 1][s * 8]);
    }
  };

  f32x4 acc[4][6];
  #pragma unroll
  for (int i = 0; i < 4; ++i)
    #pragma unroll
    for (int j = 0; j < 6; ++j)
      acc[i][j] = f32x4{0.f, 0.f, 0.f, 0.f};

  // per-lane LDS read offsets (u16 units)
  int rbase[6];
  #pragma unroll
  for (int nf = 0; nf < 6; ++nf) {
    int pg = 3 * wc + (nf >> 1);
    int col = (pg >> 2) * 128 + (pg & 3) * 16 + (nf & 1) * 64 + lq;
    rbase[nf] = col * BK;
  }
  const int aRow0 = (wr * 64 + lq) * BK;
  int qsw[2];
  qsw[0] = ((0 + lr) ^ (lq & 7)) * 8;
  qsw[1] = ((4 + lr) ^ (lq & 7)) * 8;

  // prologue: A0[2] B0[6] B1[6] = 14 loads; vmcnt(6) -> A0+B0 landed, B1 in flight
  stA(0); stB(0, 0); stB(0, 1); stB(0, 2); stB(1, 0); stB(1, 1); stB(1, 2);
  asm volatile("s_waitcnt vmcnt(6)" ::: "memory");
  GBAR();

  for (int ti = 0; ti < NT_K / 2; ++ti) {
    const int t0 = 2 * ti, t1 = t0 + 1;
    const bool nl = (ti < NT_K / 2 - 1);

    #pragma unroll
    for (int hp = 0; hp < 2; ++hp) {      // hp=0: tile t0 (buf0), hp=1: t1 (buf1)
      const u16* Ap = lsA[hp];
      const u16* Bp = lsB[hp];
      bf16x8 bfr[6][2];

      #pragma unroll
      for (int ph = 0; ph < 2; ++ph) {
        // ---- ds_read register subtile ----
        if (ph == 0) {
          #pragma unroll
          for (int nf = 0; nf < 6; ++nf)
            #pragma unroll
            for (int kk = 0; kk < 2; ++kk)
              bfr[nf][kk] = *(const bf16x8*)(Bp + rbase[nf] + qsw[kk]);
        }
        bf16x8 af[2][2];
        #pragma unroll
        for (int mfl = 0; mfl < 2; ++mfl)
          #pragma unroll
          for (int kk = 0; kk < 2; ++kk)
            af[mfl][kk] = *(const bf16x8*)(Ap + aRow0 + ((ph * 2 + mfl) * 16) * BK + qsw[kk]);

        // ---- stage schedule (R4-mirrored; hazards & vmcnt ledger in R12 notes) ----
        if (hp == 0) {
          if (ph == 0) {
            stA(t1);
          } else {
            if (nl) {
              stB(t0 + 2, 0); stB(t0 + 2, 1);
              asm volatile("s_waitcnt vmcnt(4)" ::: "memory");  // lands B(t1)+A(t1)
            } else {
              asm volatile("s_waitcnt vmcnt(0)" ::: "memory");  // drain for final tile
            }
          }
        } else {
          if (ph == 0) {
            if (nl) { stA(t0 + 2); stB(t0 + 2, 2); }
          } else {
            if (nl) {
              stB(t1 + 2, 0); stB(t1 + 2, 1); stB(t1 + 2, 2);
              asm volatile("s_waitcnt vmcnt(6)" ::: "memory");  // lands tile t0+2
            }
          }
        }
        if (ph == 0) asm volatile("s_waitcnt lgkmcnt(8)" ::: "memory");  // partial drain of 16-read phase

        GBAR();
        WLGKM0();
        __builtin_amdgcn_s_setprio(1);
        #pragma unroll
        for (int kk = 0; kk < 2; ++kk)
          #pragma unroll
          for (int mfl = 0; mfl < 2; ++mfl)
            #pragma unroll
            for (int nf = 0; nf < 6; ++nf)
              acc[ph * 2 + mfl][nf] = __builtin_amdgcn_mfma_f32_16x16x32_bf16(
                  af[mfl][kk], bfr[nf][kk], acc[ph * 2 + mfl][nf], 0, 0, 0);
        __builtin_amdgcn_s_setprio(0);
        GBAR();
      }
    }
  }

  // ---------------- epilogue (fused bias + RoPE / V-transpose, per pair-group) ----------------
  const int m0w = m0 + wr * 64;
  const int bxH = n0 >> 7;                 // = 3 * blockIdx.x
  #pragma unroll
  for (int pl = 0; pl < 3; ++pl) {
    const int pg = 3 * wc + pl;
    const int j = pg >> 2;                 // head within tile (0..2)
    const int s4 = pg & 3;                 // 16-col strip within half-head
    const int H = bxH + j;                 // absolute head index (0..47)
    const int w = H >> 4;                  // 0=q, 1=k, 2=v
    const int h = H & 15;
    const int d1 = s4 * 16 + lq;           // d within head, in [0,64); partner d1+64
    const float b1 = bias[n0 + j * 128 + d1];
    const float b2 = bias[n0 + j * 128 + d1 + 64];

    if (w == 2) {
      // V: transpose to [B,H,D,SEQP], 4 consecutive s per 8B store
      #pragma unroll
      for (int mf = 0; mf < 4; ++mf) {
        int mg0 = m0w + mf * 16 + lr * 4;
        int b = mg0 >> 11, s0 = mg0 & 2047;
        ushort4 pk;
        pk.x = f2bf(acc[mf][2 * pl][0] + b1);
        pk.y = f2bf(acc[mf][2 * pl][1] + b1);
        pk.z = f2bf(acc[mf][2 * pl][2] + b1);
        pk.w = f2bf(acc[mf][2 * pl][3] + b1);
        *(ushort4*)(vbt + ((size_t)(b * NH + h) * HD + d1) * SEQP + s0) = pk;
        pk.x = f2bf(acc[mf][2 * pl + 1][0] + b2);
        pk.y = f2bf(acc[mf][2 * pl + 1][1] + b2);
        pk.z = f2bf(acc[mf][2 * pl + 1][2] + b2);
        pk.w = f2bf(acc[mf][2 * pl + 1][3] + b2);
        *(ushort4*)(vbt + ((size_t)(b * NH + h) * HD + d1 + 64) * SEQP + s0) = pk;
      }
    } else {
      u16* basep = (w == 0) ? qb : kb;
      const float qs = (w == 0) ? 0.12751569843736827f : 1.0f;  // log2(e)/sqrt(128) into q
      #pragma unroll
      for (int mf = 0; mf < 4; ++mf)
        #pragma unroll
        for (int r = 0; r < 4; ++r) {
          int mg = m0w + mf * 16 + lr * 4 + r;
          int b = mg >> 11, s = mg & 2047;
          u16* dst = basep + ((size_t)(b * NH + h) * SEQ + s) * HD;
          float c1 = acc[mf][2 * pl][r]     + b1;
          float c2 = acc[mf][2 * pl + 1][r] + b2;
          float2 s1 = tab[s * HD + d1];
          float2 s2 = tab[s * HD + d1 + 64];
          dst[d1]      = f2bf((c1 * s1.x - c2 * s1.y) * qs);
          dst[d1 + 64] = f2bf((c2 * s2.x + c1 * s2.y) * qs);
        }
    }
  }
}

// ---------------- flash attention: QT=256, KT=64; R16 overlap + HW bf16 pack ----------------
// (R16 form + R20: P->bf16 pack via v_cvt_pk_bf16_f32 (HW RNE, bit-identical
// to the manual f2bf for finite inputs) — replaces ~140 VALU ops/wave/tile of
// manual rounding on the softmax critical path with 16 cvt_pk instrs.)
__global__ __launch_bounds__(512, 1) void k_flash(
    const u16* __restrict__ qb, const u16* __restrict__ kb,
    const u16* __restrict__ vbt, float* __restrict__ out)
{
  __shared__ __align__(16) u16 lsK[2][KT * HD];   // [key][d]  16 KB x2
  __shared__ __align__(16) u16 lsV[2][HD * KT];   // [d][key]  16 KB x2
  __shared__ __align__(16) u16 lsP[8][WQ * KT];   // per-wave [qrow][key], 4 KB x8

  const int tid = threadIdx.x;            // 0..511
  const int wave = tid >> 6, lane = tid & 63;
  const int lq = lane & 15, lr = lane >> 4;
  const int i = blockIdx.x;               // 0..255
  const int xcd = i & 7, j = i >> 3;      // j: 0..31
  const int bh = xcd * 4 + (j >> 3);      // 4 heads per XCD
  const int q0 = (j & 7) * QT;
  const u16* Qg = qb + ((size_t)bh * SEQ + q0 + wave * WQ) * HD;
  const u16* Kg = kb + (size_t)bh * SEQ * HD;
  const u16* Vg = vbt + (size_t)bh * HD * SEQP;

  auto stage = [&](int tile, int buf) {
    const int k0 = tile * KT;
    #pragma unroll
    for (int ii = 0; ii < 2; ++ii) {
      int c = tid + ii * 512;             // 0..1023 (16 KB K tile)
      int key = c >> 4, grp = c & 15;
      async16(Kg + (size_t)(k0 + key) * HD + ((grp ^ (key & 7)) * 8), lsK[buf] + c * 8);
    }
    #pragma unroll
    for (int ii = 0; ii < 2; ++ii) {
      int c = tid + ii * 512;             // 0..1023 (16 KB V tile)
      int d = c >> 3, g2 = c & 7;
      async16(Vg + (size_t)d * SEQP + k0 + ((g2 ^ ((d >> 1) & 7)) * 8), lsV[buf] + c * 8);
    }
  };

  stage(0, 0);

  bf16x8 qf[2][4];
  #pragma unroll
  for (int qq = 0; qq < 2; ++qq)
    #pragma unroll
    for (int ks = 0; ks < 4; ++ks)
      qf[qq][ks] = *(const bf16x8*)(Qg + (size_t)(qq * 16 + lq) * HD + ks * 32 + lr * 8);

  f32x4 acc_o[2][8];
  float lsum[2] = {0.f, 0.f};
  #pragma unroll
  for (int mb = 0; mb < 2; ++mb)
    #pragma unroll
    for (int nb = 0; nb < 8; ++nb) acc_o[mb][nb] = f32x4{0.f, 0.f, 0.f, 0.f};

  for (int t = 0; t < NTILE; ++t) {
    const int p = t & 1;
    __syncthreads();                 // drains stage(t); all waves done with buf 1-p
    if (t + 1 < NTILE) stage(t + 1, 1 - p);

    // S^T = K Q^T : 64 keys x 32 q-rows per wave
    f32x4 sacc[4][2];
    #pragma unroll
    for (int kbi = 0; kbi < 4; ++kbi)
      #pragma unroll
      for (int qq = 0; qq < 2; ++qq) sacc[kbi][qq] = f32x4{0.f, 0.f, 0.f, 0.f};
    #pragma unroll
    for (int ks = 0; ks < 4; ++ks) {
      bf16x8 kf[4];
      #pragma unroll
      for (int kbi = 0; kbi < 4; ++kbi) {
        int key = kbi * 16 + lq;
        int g = (ks * 4 + lr) ^ (key & 7);
        kf[kbi] = *(const bf16x8*)(lsK[p] + key * HD + g * 8);
      }
      #pragma unroll
      for (int kbi = 0; kbi < 4; ++kbi)
        #pragma unroll
        for (int qq = 0; qq < 2; ++qq)
          sacc[kbi][qq] = __builtin_amdgcn_mfma_f32_16x16x32_bf16(kf[kbi], qf[qq][ks], sacc[kbi][qq], 0, 0, 0);
    }

    // softmax + PV in two key-halves (overlap exp/pack of half 1 with PV of half 0)
    #pragma unroll
    for (int half = 0; half < 2; ++half) {
      // P = exp2(S) for kbi {2*half, 2*half+1}; HW-packed b64 writes
      #pragma unroll
      for (int kb2 = 0; kb2 < 2; ++kb2) {
        int kbi = half * 2 + kb2;
        #pragma unroll
        for (int qq = 0; qq < 2; ++qq) {
          float p0 = __builtin_amdgcn_exp2f(sacc[kbi][qq][0]);
          float p1 = __builtin_amdgcn_exp2f(sacc[kbi][qq][1]);
          float p2 = __builtin_amdgcn_exp2f(sacc[kbi][qq][2]);
          float p3 = __builtin_amdgcn_exp2f(sacc[kbi][qq][3]);
          lsum[qq] += (p0 + p1) + (p2 + p3);
          int row = qq * 16 + lq;
          int g = kbi * 4 + lr;                        // 0..15 (8B groups in 128B row)
          int gp = g ^ (row & 6) ^ ((row & 8) >> 1);
          uint2 pk;
          pk.x = cvtpk_bf16(p0, p1);
          pk.y = cvtpk_bf16(p2, p3);
          *(uint2*)(lsP[wave] + row * KT + gp * 4) = pk;
        }
      }

      // O += P V for this 32-key slot
      bf16x8 ap[2];
      #pragma unroll
      for (int mb = 0; mb < 2; ++mb) {
        int row = mb * 16 + lq;
        int sw = (row & 6) ^ ((row & 8) >> 1);
        int gb = (half * 8 + 2 * lr) ^ sw;             // even -> 16B-aligned
        ap[mb] = *(const bf16x8*)(lsP[wave] + row * KT + gb * 4);
      }
      #pragma unroll
      for (int nb = 0; nb < 8; ++nb) {
        int d = nb * 16 + lq;
        int q8 = (half * 4 + lr) ^ ((d >> 1) & 7);
        bf16x8 bv = *(const bf16x8*)(lsV[p] + d * KT + q8 * 8);
        #pragma unroll
        for (int mb = 0; mb < 2; ++mb)
          acc_o[mb][nb] = __builtin_amdgcn_mfma_f32_16x16x32_bf16(ap[mb], bv, acc_o[mb][nb], 0, 0, 0);
      }
    }
  }

  float inv[2];
  #pragma unroll
  for (int qq = 0; qq < 2; ++qq) {
    float s = lsum[qq];
    s += __shfl_xor(s, 16);
    s += __shfl_xor(s, 32);
    inv[qq] = 1.0f / s;
  }
  const int b = bh >> 4, h = bh & 15;
  #pragma unroll
  for (int mb = 0; mb < 2; ++mb)
    #pragma unroll
    for (int r = 0; r < 4; ++r) {
      float iv = __shfl(inv[mb], lr * 4 + r);
      int row = wave * WQ + mb * 16 + lr * 4 + r;
      int sq = q0 + row;
      float* op = out + (((size_t)b * SEQ + sq) * NH + h) * HD;
      #pragma unroll
      for (int nb = 0; nb < 8; ++nb)
        op[nb * 16 + lq] = acc_o[mb][nb][r] * iv;
    }
}

// ---------------- launch ----------------

extern "C" void kernel_launch(void* const* d_in, const int* in_sizes, int n_in,
                              void* d_out, int out_size, void* d_ws, size_t ws_size,
                              hipStream_t stream) {
  (void)in_sizes; (void)n_in; (void)out_size; (void)ws_size;
  const float* x    = (const float*)d_in[0];
  const float* W    = (const float*)d_in[1];
  const float* bias = (const float*)d_in[2];
  float* out = (float*)d_out;

  char* p = (char*)d_ws;
  u16* xb  = (u16*)p;  p += (size_t)MM * EMB * 2;                     // 16.8 MB
  u16* wt  = (u16*)p;  p += (size_t)N3 * EMB * 2;                     // 25.2 MB
  u16* qb  = (u16*)p;  p += (size_t)NUM_B * NH * SEQ * HD * 2;        // 16.8 MB
  u16* kb  = (u16*)p;  p += (size_t)NUM_B * NH * SEQ * HD * 2;        // 16.8 MB
  u16* vbt = (u16*)p;  p += (size_t)NUM_B * NH * HD * SEQP * 2;       // 17.0 MB
  float2* tab = (float2*)p;                                           // 2.1 MB

  k_prep<<<CVT_BLKS + TRN_BX * (EMB / 32), 256, 0, stream>>>(x, xb, tab, W, wt);
  k_gemm_qkv<<<dim3(N3 / BN, MM / BM), 512, 0, stream>>>(xb, wt, bias, tab, qb, kb, vbt);
  k_flash<<<SEQ / QT * NUM_B * NH, 512, 0, stream>>>(qb, kb, vbt, out);
}

// Round 21
// 210.264 us; speedup vs baseline: 1.1508x; 1.0472x over previous
//
#include <hip/hip_runtime.h>
#include <stdint.h>

typedef unsigned short u16;
typedef __attribute__((ext_vector_type(8))) short bf16x8;   // 8 bf16 = 4 VGPRs
typedef __attribute__((ext_vector_type(4))) float f32x4;

#define NUM_B 2
#define SEQ   2048
#define SEQP  2080      // padded V row stride
#define NH    16
#define HD    128
#define EMB   2048      // NH*HD
#define N3    6144      // 3*EMB
#define MM    4096      // NUM_B*SEQ
#define QT    256       // flash q-rows per block (8 waves)
#define WQ    32        // flash q-rows per wave
#define KT    64        // flash keys per k-tile
#define NTILE (SEQ / KT)

// ---- GEMM tile params: 128x384, BK=64, 8 waves -> 512 blocks = 2.0 exact rounds ----
// (R12 form, the empirical optimum over 8 probed structures: ~131 us, 32.4%.)
#define BM 128
#define BN 384
#define BK 64
#define NT_K (EMB / BK)   // 32 K-tiles, 16 iterations of 2

__device__ __forceinline__ u16 f2bf(float f) {
  union { float f; unsigned u; } c; c.f = f;
  return (u16)((c.u + 0x7FFFu + ((c.u >> 16) & 1u)) >> 16);   // RNE
}
__device__ __forceinline__ void async16(const void* g, void* l) {
  __builtin_amdgcn_global_load_lds(
      (const __attribute__((address_space(1))) void*)g,
      (__attribute__((address_space(3))) void*)l, 16, 0, 0);
}
// HW packed f32->bf16 (RNE; bit-identical to f2bf for finite inputs).
// T12 recipe: no builtin on gfx950, inline asm is the supported form.
__device__ __forceinline__ uint32_t cvtpk_bf16(float lo, float hi) {
  uint32_t r;
  asm("v_cvt_pk_bf16_f32 %0, %1, %2" : "=v"(r) : "v"(lo), "v"(hi));
  return r;
}

#define GBAR()   asm volatile("s_barrier" ::: "memory")
#define WLGKM0() asm volatile("s_waitcnt lgkmcnt(0)" ::: "memory")

// ---------------- prep: fused bf16-cast (+sincos table) and W-transpose ----------------
#define CVT_BLKS (MM * EMB / 4 / 256)          // 8192
#define TRN_BX   (N3 / 32)                     // 192
__global__ void k_prep(const float* __restrict__ x, u16* __restrict__ xb,
                       float2* __restrict__ tab,
                       const float* __restrict__ W, u16* __restrict__ Wt) {
  __shared__ float t[32][33];
  const int bid = blockIdx.x;
  if (bid < CVT_BLKS) {
    int i = bid * 256 + threadIdx.x;
    const float4 v = ((const float4*)x)[i];
    ushort4 o;
    o.x = f2bf(v.x); o.y = f2bf(v.y); o.z = f2bf(v.z); o.w = f2bf(v.w);
    ((ushort4*)xb)[i] = o;
    if (i < SEQ * HD) {
      double tt = (double)i;
      tab[i] = make_float2((float)cos(tt), (float)sin(tt));
    }
  } else {
    int b2 = bid - CVT_BLKS;
    int n0 = (b2 % TRN_BX) * 32, k0 = (b2 / TRN_BX) * 32;
    int tx = threadIdx.x & 31, ty = threadIdx.x >> 5;   // 32 x 8
    #pragma unroll
    for (int i = ty; i < 32; i += 8)
      t[i][tx] = W[(size_t)(k0 + i) * N3 + n0 + tx];
    __syncthreads();
    #pragma unroll
    for (int i = ty; i < 32; i += 8)
      Wt[(size_t)(n0 + i) * EMB + k0 + tx] = f2bf(t[tx][i]);
  }
}

// ---------------- QKV GEMM: 128x384, R4-style schedule, ZERO grid tail ----------------
// (R12 form; R21 change: s_setprio REMOVED from the MFMA clusters — this
// kernel is 8-wave barrier-lockstep, exactly m190's regime where setprio in
// lockstep GEMM measured −1.5% (no wave role diversity; all waves raise
// priority together). Same reasoning removed it from flash in R16.
// Everything else unchanged: ~131 us, MfmaUtil 32.4, no spill.)
__global__ __launch_bounds__(512, 2) void k_gemm_qkv(
    const u16* __restrict__ xb, const u16* __restrict__ wt,
    const float* __restrict__ bias, const float2* __restrict__ tab,
    u16* __restrict__ qb, u16* __restrict__ kb, u16* __restrict__ vbt)
{
  __shared__ __align__(16) u16 lsA[2][BM * BK];   // 16 KB x2
  __shared__ __align__(16) u16 lsB[2][BN * BK];   // 48 KB x2  (128 KB total)
  const int tid = threadIdx.x;            // 0..511
  const int wave = tid >> 6, lane = tid & 63;
  const int lq = lane & 15, lr = lane >> 4;
  const int wr = wave >> 2, wc = wave & 3;
  const int m0 = blockIdx.y * BM, n0 = blockIdx.x * BN;

  auto stA = [&](int t) {                 // whole 128x64 A tile: 2 loads/thread
    const int kt = t * BK;
    #pragma unroll
    for (int ii = 0; ii < 2; ++ii) {
      int s = ii * 512 + tid;             // 16B slot 0..1023
      int row = s >> 3, gq = (s & 7) ^ (row & 7);
      async16(xb + (size_t)(m0 + row) * EMB + kt + gq * 8, &lsA[t & 1][s * 8]);
    }
  };
  auto stB = [&](int t, int u) {          // one 128-row third: 2 loads/thread
    const int kt = t * BK;
    #pragma unroll
    for (int ii = 0; ii < 2; ++ii) {
      int s = u * 1024 + ii * 512 + tid;  // 16B slot within B tile
      int row = s >> 3, gq = (s & 7) ^ (row & 7);
      async16(wt + (size_t)(n0 + row) * EMB + kt + gq * 8, &lsB[t & 1][s * 8]);
    }
  };

  f32x4 acc[4][6];
  #pragma unroll
  for (int i = 0; i < 4; ++i)
    #pragma unroll
    for (int j = 0; j < 6; ++j)
      acc[i][j] = f32x4{0.f, 0.f, 0.f, 0.f};

  // per-lane LDS read offsets (u16 units)
  int rbase[6];
  #pragma unroll
  for (int nf = 0; nf < 6; ++nf) {
    int pg = 3 * wc + (nf >> 1);
    int col = (pg >> 2) * 128 + (pg & 3) * 16 + (nf & 1) * 64 + lq;
    rbase[nf] = col * BK;
  }
  const int aRow0 = (wr * 64 + lq) * BK;
  int qsw[2];
  qsw[0] = ((0 + lr) ^ (lq & 7)) * 8;
  qsw[1] = ((4 + lr) ^ (lq & 7)) * 8;

  // prologue: A0[2] B0[6] B1[6] = 14 loads; vmcnt(6) -> A0+B0 landed, B1 in flight
  stA(0); stB(0, 0); stB(0, 1); stB(0, 2); stB(1, 0); stB(1, 1); stB(1, 2);
  asm volatile("s_waitcnt vmcnt(6)" ::: "memory");
  GBAR();

  for (int ti = 0; ti < NT_K / 2; ++ti) {
    const int t0 = 2 * ti, t1 = t0 + 1;
    const bool nl = (ti < NT_K / 2 - 1);

    #pragma unroll
    for (int hp = 0; hp < 2; ++hp) {      // hp=0: tile t0 (buf0), hp=1: t1 (buf1)
      const u16* Ap = lsA[hp];
      const u16* Bp = lsB[hp];
      bf16x8 bfr[6][2];

      #pragma unroll
      for (int ph = 0; ph < 2; ++ph) {
        // ---- ds_read register subtile ----
        if (ph == 0) {
          #pragma unroll
          for (int nf = 0; nf < 6; ++nf)
            #pragma unroll
            for (int kk = 0; kk < 2; ++kk)
              bfr[nf][kk] = *(const bf16x8*)(Bp + rbase[nf] + qsw[kk]);
        }
        bf16x8 af[2][2];
        #pragma unroll
        for (int mfl = 0; mfl < 2; ++mfl)
          #pragma unroll
          for (int kk = 0; kk < 2; ++kk)
            af[mfl][kk] = *(const bf16x8*)(Ap + aRow0 + ((ph * 2 + mfl) * 16) * BK + qsw[kk]);

        // ---- stage schedule (R4-mirrored; hazards & vmcnt ledger in R12 notes) ----
        if (hp == 0) {
          if (ph == 0) {
            stA(t1);
          } else {
            if (nl) {
              stB(t0 + 2, 0); stB(t0 + 2, 1);
              asm volatile("s_waitcnt vmcnt(4)" ::: "memory");  // lands B(t1)+A(t1)
            } else {
              asm volatile("s_waitcnt vmcnt(0)" ::: "memory");  // drain for final tile
            }
          }
        } else {
          if (ph == 0) {
            if (nl) { stA(t0 + 2); stB(t0 + 2, 2); }
          } else {
            if (nl) {
              stB(t1 + 2, 0); stB(t1 + 2, 1); stB(t1 + 2, 2);
              asm volatile("s_waitcnt vmcnt(6)" ::: "memory");  // lands tile t0+2
            }
          }
        }
        if (ph == 0) asm volatile("s_waitcnt lgkmcnt(8)" ::: "memory");  // partial drain of 16-read phase

        GBAR();
        WLGKM0();
        #pragma unroll
        for (int kk = 0; kk < 2; ++kk)
          #pragma unroll
          for (int mfl = 0; mfl < 2; ++mfl)
            #pragma unroll
            for (int nf = 0; nf < 6; ++nf)
              acc[ph * 2 + mfl][nf] = __builtin_amdgcn_mfma_f32_16x16x32_bf16(
                  af[mfl][kk], bfr[nf][kk], acc[ph * 2 + mfl][nf], 0, 0, 0);
        GBAR();
      }
    }
  }

  // ---------------- epilogue (fused bias + RoPE / V-transpose, per pair-group) ----------------
  const int m0w = m0 + wr * 64;
  const int bxH = n0 >> 7;                 // = 3 * blockIdx.x
  #pragma unroll
  for (int pl = 0; pl < 3; ++pl) {
    const int pg = 3 * wc + pl;
    const int j = pg >> 2;                 // head within tile (0..2)
    const int s4 = pg & 3;                 // 16-col strip within half-head
    const int H = bxH + j;                 // absolute head index (0..47)
    const int w = H >> 4;                  // 0=q, 1=k, 2=v
    const int h = H & 15;
    const int d1 = s4 * 16 + lq;           // d within head, in [0,64); partner d1+64
    const float b1 = bias[n0 + j * 128 + d1];
    const float b2 = bias[n0 + j * 128 + d1 + 64];

    if (w == 2) {
      // V: transpose to [B,H,D,SEQP], 4 consecutive s per 8B store
      #pragma unroll
      for (int mf = 0; mf < 4; ++mf) {
        int mg0 = m0w + mf * 16 + lr * 4;
        int b = mg0 >> 11, s0 = mg0 & 2047;
        ushort4 pk;
        pk.x = f2bf(acc[mf][2 * pl][0] + b1);
        pk.y = f2bf(acc[mf][2 * pl][1] + b1);
        pk.z = f2bf(acc[mf][2 * pl][2] + b1);
        pk.w = f2bf(acc[mf][2 * pl][3] + b1);
        *(ushort4*)(vbt + ((size_t)(b * NH + h) * HD + d1) * SEQP + s0) = pk;
        pk.x = f2bf(acc[mf][2 * pl + 1][0] + b2);
        pk.y = f2bf(acc[mf][2 * pl + 1][1] + b2);
        pk.z = f2bf(acc[mf][2 * pl + 1][2] + b2);
        pk.w = f2bf(acc[mf][2 * pl + 1][3] + b2);
        *(ushort4*)(vbt + ((size_t)(b * NH + h) * HD + d1 + 64) * SEQP + s0) = pk;
      }
    } else {
      u16* basep = (w == 0) ? qb : kb;
      const float qs = (w == 0) ? 0.12751569843736827f : 1.0f;  // log2(e)/sqrt(128) into q
      #pragma unroll
      for (int mf = 0; mf < 4; ++mf)
        #pragma unroll
        for (int r = 0; r < 4; ++r) {
          int mg = m0w + mf * 16 + lr * 4 + r;
          int b = mg >> 11, s = mg & 2047;
          u16* dst = basep + ((size_t)(b * NH + h) * SEQ + s) * HD;
          float c1 = acc[mf][2 * pl][r]     + b1;
          float c2 = acc[mf][2 * pl + 1][r] + b2;
          float2 s1 = tab[s * HD + d1];
          float2 s2 = tab[s * HD + d1 + 64];
          dst[d1]      = f2bf((c1 * s1.x - c2 * s1.y) * qs);
          dst[d1 + 64] = f2bf((c2 * s2.x + c1 * s2.y) * qs);
        }
    }
  }
}

// ---------------- flash attention: QT=256, KT=64; R16 overlap + HW bf16 pack ----------------
// (R20 form, verified 220.2 us: no setprio in lockstep; softmax/PV split into
// two key-halves; P->bf16 pack via v_cvt_pk_bf16_f32. UNCHANGED.)
__global__ __launch_bounds__(512, 1) void k_flash(
    const u16* __restrict__ qb, const u16* __restrict__ kb,
    const u16* __restrict__ vbt, float* __restrict__ out)
{
  __shared__ __align__(16) u16 lsK[2][KT * HD];   // [key][d]  16 KB x2
  __shared__ __align__(16) u16 lsV[2][HD * KT];   // [d][key]  16 KB x2
  __shared__ __align__(16) u16 lsP[8][WQ * KT];   // per-wave [qrow][key], 4 KB x8

  const int tid = threadIdx.x;            // 0..511
  const int wave = tid >> 6, lane = tid & 63;
  const int lq = lane & 15, lr = lane >> 4;
  const int i = blockIdx.x;               // 0..255
  const int xcd = i & 7, j = i >> 3;      // j: 0..31
  const int bh = xcd * 4 + (j >> 3);      // 4 heads per XCD
  const int q0 = (j & 7) * QT;
  const u16* Qg = qb + ((size_t)bh * SEQ + q0 + wave * WQ) * HD;
  const u16* Kg = kb + (size_t)bh * SEQ * HD;
  const u16* Vg = vbt + (size_t)bh * HD * SEQP;

  auto stage = [&](int tile, int buf) {
    const int k0 = tile * KT;
    #pragma unroll
    for (int ii = 0; ii < 2; ++ii) {
      int c = tid + ii * 512;             // 0..1023 (16 KB K tile)
      int key = c >> 4, grp = c & 15;
      async16(Kg + (size_t)(k0 + key) * HD + ((grp ^ (key & 7)) * 8), lsK[buf] + c * 8);
    }
    #pragma unroll
    for (int ii = 0; ii < 2; ++ii) {
      int c = tid + ii * 512;             // 0..1023 (16 KB V tile)
      int d = c >> 3, g2 = c & 7;
      async16(Vg + (size_t)d * SEQP + k0 + ((g2 ^ ((d >> 1) & 7)) * 8), lsV[buf] + c * 8);
    }
  };

  stage(0, 0);

  bf16x8 qf[2][4];
  #pragma unroll
  for (int qq = 0; qq < 2; ++qq)
    #pragma unroll
    for (int ks = 0; ks < 4; ++ks)
      qf[qq][ks] = *(const bf16x8*)(Qg + (size_t)(qq * 16 + lq) * HD + ks * 32 + lr * 8);

  f32x4 acc_o[2][8];
  float lsum[2] = {0.f, 0.f};
  #pragma unroll
  for (int mb = 0; mb < 2; ++mb)
    #pragma unroll
    for (int nb = 0; nb < 8; ++nb) acc_o[mb][nb] = f32x4{0.f, 0.f, 0.f, 0.f};

  for (int t = 0; t < NTILE; ++t) {
    const int p = t & 1;
    __syncthreads();                 // drains stage(t); all waves done with buf 1-p
    if (t + 1 < NTILE) stage(t + 1, 1 - p);

    // S^T = K Q^T : 64 keys x 32 q-rows per wave
    f32x4 sacc[4][2];
    #pragma unroll
    for (int kbi = 0; kbi < 4; ++kbi)
      #pragma unroll
      for (int qq = 0; qq < 2; ++qq) sacc[kbi][qq] = f32x4{0.f, 0.f, 0.f, 0.f};
    #pragma unroll
    for (int ks = 0; ks < 4; ++ks) {
      bf16x8 kf[4];
      #pragma unroll
      for (int kbi = 0; kbi < 4; ++kbi) {
        int key = kbi * 16 + lq;
        int g = (ks * 4 + lr) ^ (key & 7);
        kf[kbi] = *(const bf16x8*)(lsK[p] + key * HD + g * 8);
      }
      #pragma unroll
      for (int kbi = 0; kbi < 4; ++kbi)
        #pragma unroll
        for (int qq = 0; qq < 2; ++qq)
          sacc[kbi][qq] = __builtin_amdgcn_mfma_f32_16x16x32_bf16(kf[kbi], qf[qq][ks], sacc[kbi][qq], 0, 0, 0);
    }

    // softmax + PV in two key-halves (overlap exp/pack of half 1 with PV of half 0)
    #pragma unroll
    for (int half = 0; half < 2; ++half) {
      // P = exp2(S) for kbi {2*half, 2*half+1}; HW-packed b64 writes
      #pragma unroll
      for (int kb2 = 0; kb2 < 2; ++kb2) {
        int kbi = half * 2 + kb2;
        #pragma unroll
        for (int qq = 0; qq < 2; ++qq) {
          float p0 = __builtin_amdgcn_exp2f(sacc[kbi][qq][0]);
          float p1 = __builtin_amdgcn_exp2f(sacc[kbi][qq][1]);
          float p2 = __builtin_amdgcn_exp2f(sacc[kbi][qq][2]);
          float p3 = __builtin_amdgcn_exp2f(sacc[kbi][qq][3]);
          lsum[qq] += (p0 + p1) + (p2 + p3);
          int row = qq * 16 + lq;
          int g = kbi * 4 + lr;                        // 0..15 (8B groups in 128B row)
          int gp = g ^ (row & 6) ^ ((row & 8) >> 1);
          uint2 pk;
          pk.x = cvtpk_bf16(p0, p1);
          pk.y = cvtpk_bf16(p2, p3);
          *(uint2*)(lsP[wave] + row * KT + gp * 4) = pk;
        }
      }

      // O += P V for this 32-key slot
      bf16x8 ap[2];
      #pragma unroll
      for (int mb = 0; mb < 2; ++mb) {
        int row = mb * 16 + lq;
        int sw = (row & 6) ^ ((row & 8) >> 1);
        int gb = (half * 8 + 2 * lr) ^ sw;             // even -> 16B-aligned
        ap[mb] = *(const bf16x8*)(lsP[wave] + row * KT + gb * 4);
      }
      #pragma unroll
      for (int nb = 0; nb < 8; ++nb) {
        int d = nb * 16 + lq;
        int q8 = (half * 4 + lr) ^ ((d >> 1) & 7);
        bf16x8 bv = *(const bf16x8*)(lsV[p] + d * KT + q8 * 8);
        #pragma unroll
        for (int mb = 0; mb < 2; ++mb)
          acc_o[mb][nb] = __builtin_amdgcn_mfma_f32_16x16x32_bf16(ap[mb], bv, acc_o[mb][nb], 0, 0, 0);
      }
    }
  }

  float inv[2];
  #pragma unroll
  for (int qq = 0; qq < 2; ++qq) {
    float s = lsum[qq];
    s += __shfl_xor(s, 16);
    s += __shfl_xor(s, 32);
    inv[qq] = 1.0f / s;
  }
  const int b = bh >> 4, h = bh & 15;
  #pragma unroll
  for (int mb = 0; mb < 2; ++mb)
    #pragma unroll
    for (int r = 0; r < 4; ++r) {
      float iv = __shfl(inv[mb], lr * 4 + r);
      int row = wave * WQ + mb * 16 + lr * 4 + r;
      int sq = q0 + row;
      float* op = out + (((size_t)b * SEQ + sq) * NH + h) * HD;
      #pragma unroll
      for (int nb = 0; nb < 8; ++nb)
        op[nb * 16 + lq] = acc_o[mb][nb][r] * iv;
    }
}

// ---------------- launch ----------------

extern "C" void kernel_launch(void* const* d_in, const int* in_sizes, int n_in,
                              void* d_out, int out_size, void* d_ws, size_t ws_size,
                              hipStream_t stream) {
  (void)in_sizes; (void)n_in; (void)out_size; (void)ws_size;
  const float* x    = (const float*)d_in[0];
  const float* W    = (const float*)d_in[1];
  const float* bias = (const float*)d_in[2];
  float* out = (float*)d_out;

  char* p = (char*)d_ws;
  u16* xb  = (u16*)p;  p += (size_t)MM * EMB * 2;                     // 16.8 MB
  u16* wt  = (u16*)p;  p += (size_t)N3 * EMB * 2;                     // 25.2 MB
  u16* qb  = (u16*)p;  p += (size_t)NUM_B * NH * SEQ * HD * 2;        // 16.8 MB
  u16* kb  = (u16*)p;  p += (size_t)NUM_B * NH * SEQ * HD * 2;        // 16.8 MB
  u16* vbt = (u16*)p;  p += (size_t)NUM_B * NH * HD * SEQP * 2;       // 17.0 MB
  float2* tab = (float2*)p;                                           // 2.1 MB

  k_prep<<<CVT_BLKS + TRN_BX * (EMB / 32), 256, 0, stream>>>(x, xb, tab, W, wt);
  k_gemm_qkv<<<dim3(N3 / BN, MM / BM), 512, 0, stream>>>(xb, wt, bias, tab, qb, kb, vbt);
  k_flash<<<SEQ / QT * NUM_B * NH, 512, 0, stream>>>(qb, kb, vbt, out);
}

// Round 22
// 208.990 us; speedup vs baseline: 1.1578x; 1.0061x over previous
//
#include <hip/hip_runtime.h>
#include <stdint.h>

typedef unsigned short u16;
typedef __attribute__((ext_vector_type(8))) short bf16x8;   // 8 bf16 = 4 VGPRs
typedef __attribute__((ext_vector_type(4))) float f32x4;

#define NUM_B 2
#define SEQ   2048
#define SEQP  2080      // padded V row stride
#define NH    16
#define HD    128
#define EMB   2048      // NH*HD
#define N3    6144      // 3*EMB
#define MM    4096      // NUM_B*SEQ
#define QT    256       // flash q-rows per block (8 waves)
#define WQ    32        // flash q-rows per wave
#define KT    64        // flash keys per k-tile
#define NTILE (SEQ / KT)

// ---- GEMM tile params: 128x384, BK=64, 8 waves -> 512 blocks = 2.0 exact rounds ----
#define BM 128
#define BN 384
#define BK 64
#define NT_K (EMB / BK)   // 32 K-tiles, 16 iterations of 2

__device__ __forceinline__ u16 f2bf(float f) {
  union { float f; unsigned u; } c; c.f = f;
  return (u16)((c.u + 0x7FFFu + ((c.u >> 16) & 1u)) >> 16);   // RNE
}
__device__ __forceinline__ void async16(const void* g, void* l) {
  __builtin_amdgcn_global_load_lds(
      (const __attribute__((address_space(1))) void*)g,
      (__attribute__((address_space(3))) void*)l, 16, 0, 0);
}
// HW packed f32->bf16 (RNE; bit-identical to f2bf for finite inputs).
__device__ __forceinline__ uint32_t cvtpk_bf16(float lo, float hi) {
  uint32_t r;
  asm("v_cvt_pk_bf16_f32 %0, %1, %2" : "=v"(r) : "v"(lo), "v"(hi));
  return r;
}

#define GBAR()   asm volatile("s_barrier" ::: "memory")

// ---------------- prep: fused bf16-cast (+sincos table) and W-transpose ----------------
#define CVT_BLKS (MM * EMB / 4 / 256)          // 8192
#define TRN_BX   (N3 / 32)                     // 192
__global__ void k_prep(const float* __restrict__ x, u16* __restrict__ xb,
                       float2* __restrict__ tab,
                       const float* __restrict__ W, u16* __restrict__ Wt) {
  __shared__ float t[32][33];
  const int bid = blockIdx.x;
  if (bid < CVT_BLKS) {
    int i = bid * 256 + threadIdx.x;
    const float4 v = ((const float4*)x)[i];
    ushort4 o;
    o.x = f2bf(v.x); o.y = f2bf(v.y); o.z = f2bf(v.z); o.w = f2bf(v.w);
    ((ushort4*)xb)[i] = o;
    if (i < SEQ * HD) {
      double tt = (double)i;
      tab[i] = make_float2((float)cos(tt), (float)sin(tt));
    }
  } else {
    int b2 = bid - CVT_BLKS;
    int n0 = (b2 % TRN_BX) * 32, k0 = (b2 / TRN_BX) * 32;
    int tx = threadIdx.x & 31, ty = threadIdx.x >> 5;   // 32 x 8
    #pragma unroll
    for (int i = ty; i < 32; i += 8)
      t[i][tx] = W[(size_t)(k0 + i) * N3 + n0 + tx];
    __syncthreads();
    #pragma unroll
    for (int i = ty; i < 32; i += 8)
      Wt[(size_t)(n0 + i) * EMB + k0 + tx] = f2bf(t[tx][i]);
  }
}

// ---------------- QKV GEMM: 128x384, MINIMAL-SYNC schedule ----------------
// R21 post-mortem: setprio removal gave −10 us (rigid scheduling hurts this
// kernel). R22: continue that gradient — drop the pre-MFMA GBAR and the
// forced lgkmcnt(0) full drain. Phase = reads; stage; [vmcnt]; MFMA (compiler
// inserts fine-grained per-use lgkmcnt, m97-proven near-optimal);
// sched_barrier(0); GBAR. One barrier per phase (2/K-tile, was 4).
// Correctness chain:
//  - staged-data publish: per-wave vmcnt(N) is asm-memory-ordered before the
//    trailing GBAR; all waves' slices landed before any wave passes it ->
//    next phase's reads safe (same ledger as R12: vmcnt(4)@hp0.ph1 lands t1,
//    vmcnt(6)@hp1.ph1 lands t0+2; never 0 in steady state).
//  - read-before-overwrite: every ds_read's data is in registers before its
//    consuming MFMA issues (compiler waitcnt); sched_barrier(0) pins the MFMA
//    cluster (and thus those waits) before the trailing GBAR (rule #18:
//    hipcc would otherwise hoist register-only MFMAs past asm barriers);
//    stage targeting a buffer is always >=1 trailing-GBAR after its last read.
// Accumulation per element is a data-dependence chain (t asc, kk asc) ->
// bit-identical regardless of MFMA issue order.
__global__ __launch_bounds__(512, 2) void k_gemm_qkv(
    const u16* __restrict__ xb, const u16* __restrict__ wt,
    const float* __restrict__ bias, const float2* __restrict__ tab,
    u16* __restrict__ qb, u16* __restrict__ kb, u16* __restrict__ vbt)
{
  __shared__ __align__(16) u16 lsA[2][BM * BK];   // 16 KB x2
  __shared__ __align__(16) u16 lsB[2][BN * BK];   // 48 KB x2  (128 KB total)
  const int tid = threadIdx.x;            // 0..511
  const int wave = tid >> 6, lane = tid & 63;
  const int lq = lane & 15, lr = lane >> 4;
  const int wr = wave >> 2, wc = wave & 3;
  const int m0 = blockIdx.y * BM, n0 = blockIdx.x * BN;

  auto stA = [&](int t) {                 // whole 128x64 A tile: 2 loads/thread
    const int kt = t * BK;
    #pragma unroll
    for (int ii = 0; ii < 2; ++ii) {
      int s = ii * 512 + tid;             // 16B slot 0..1023
      int row = s >> 3, gq = (s & 7) ^ (row & 7);
      async16(xb + (size_t)(m0 + row) * EMB + kt + gq * 8, &lsA[t & 1][s * 8]);
    }
  };
  auto stB = [&](int t, int u) {          // one 128-row third: 2 loads/thread
    const int kt = t * BK;
    #pragma unroll
    for (int ii = 0; ii < 2; ++ii) {
      int s = u * 1024 + ii * 512 + tid;  // 16B slot within B tile
      int row = s >> 3, gq = (s & 7) ^ (row & 7);
      async16(wt + (size_t)(n0 + row) * EMB + kt + gq * 8, &lsB[t & 1][s * 8]);
    }
  };

  f32x4 acc[4][6];
  #pragma unroll
  for (int i = 0; i < 4; ++i)
    #pragma unroll
    for (int j = 0; j < 6; ++j)
      acc[i][j] = f32x4{0.f, 0.f, 0.f, 0.f};

  // per-lane LDS read offsets (u16 units)
  int rbase[6];
  #pragma unroll
  for (int nf = 0; nf < 6; ++nf) {
    int pg = 3 * wc + (nf >> 1);
    int col = (pg >> 2) * 128 + (pg & 3) * 16 + (nf & 1) * 64 + lq;
    rbase[nf] = col * BK;
  }
  const int aRow0 = (wr * 64 + lq) * BK;
  int qsw[2];
  qsw[0] = ((0 + lr) ^ (lq & 7)) * 8;
  qsw[1] = ((4 + lr) ^ (lq & 7)) * 8;

  // prologue: A0[2] B0[6] B1[6] = 14 loads; vmcnt(6) -> A0+B0 landed, B1 in flight
  stA(0); stB(0, 0); stB(0, 1); stB(0, 2); stB(1, 0); stB(1, 1); stB(1, 2);
  asm volatile("s_waitcnt vmcnt(6)" ::: "memory");
  GBAR();

  for (int ti = 0; ti < NT_K / 2; ++ti) {
    const int t0 = 2 * ti, t1 = t0 + 1;
    const bool nl = (ti < NT_K / 2 - 1);

    #pragma unroll
    for (int hp = 0; hp < 2; ++hp) {      // hp=0: tile t0 (buf0), hp=1: t1 (buf1)
      const u16* Ap = lsA[hp];
      const u16* Bp = lsB[hp];
      bf16x8 bfr[6][2];

      #pragma unroll
      for (int ph = 0; ph < 2; ++ph) {
        // ---- ds_read register subtile ----
        if (ph == 0) {
          #pragma unroll
          for (int nf = 0; nf < 6; ++nf)
            #pragma unroll
            for (int kk = 0; kk < 2; ++kk)
              bfr[nf][kk] = *(const bf16x8*)(Bp + rbase[nf] + qsw[kk]);
        }
        bf16x8 af[2][2];
        #pragma unroll
        for (int mfl = 0; mfl < 2; ++mfl)
          #pragma unroll
          for (int kk = 0; kk < 2; ++kk)
            af[mfl][kk] = *(const bf16x8*)(Ap + aRow0 + ((ph * 2 + mfl) * 16) * BK + qsw[kk]);

        // ---- stage schedule (R12 ledger; vmcnt per-wave, published by trailing GBAR) ----
        if (hp == 0) {
          if (ph == 0) {
            stA(t1);
          } else {
            if (nl) {
              stB(t0 + 2, 0); stB(t0 + 2, 1);
              asm volatile("s_waitcnt vmcnt(4)" ::: "memory");  // lands B(t1)+A(t1)
            } else {
              asm volatile("s_waitcnt vmcnt(0)" ::: "memory");  // drain for final tile
            }
          }
        } else {
          if (ph == 0) {
            if (nl) { stA(t0 + 2); stB(t0 + 2, 2); }
          } else {
            if (nl) {
              stB(t1 + 2, 0); stB(t1 + 2, 1); stB(t1 + 2, 2);
              asm volatile("s_waitcnt vmcnt(6)" ::: "memory");  // lands tile t0+2
            }
          }
        }

        // ---- MFMA cluster: compiler schedules per-operand lgkmcnt waits ----
        #pragma unroll
        for (int kk = 0; kk < 2; ++kk)
          #pragma unroll
          for (int mfl = 0; mfl < 2; ++mfl)
            #pragma unroll
            for (int nf = 0; nf < 6; ++nf)
              acc[ph * 2 + mfl][nf] = __builtin_amdgcn_mfma_f32_16x16x32_bf16(
                  af[mfl][kk], bfr[nf][kk], acc[ph * 2 + mfl][nf], 0, 0, 0);
        __builtin_amdgcn_sched_barrier(0);   // pin MFMAs (and their waits) before the barrier
        GBAR();
      }
    }
  }

  // ---------------- epilogue (fused bias + RoPE / V-transpose, per pair-group) ----------------
  const int m0w = m0 + wr * 64;
  const int bxH = n0 >> 7;                 // = 3 * blockIdx.x
  #pragma unroll
  for (int pl = 0; pl < 3; ++pl) {
    const int pg = 3 * wc + pl;
    const int j = pg >> 2;                 // head within tile (0..2)
    const int s4 = pg & 3;                 // 16-col strip within half-head
    const int H = bxH + j;                 // absolute head index (0..47)
    const int w = H >> 4;                  // 0=q, 1=k, 2=v
    const int h = H & 15;
    const int d1 = s4 * 16 + lq;           // d within head, in [0,64); partner d1+64
    const float b1 = bias[n0 + j * 128 + d1];
    const float b2 = bias[n0 + j * 128 + d1 + 64];

    if (w == 2) {
      // V: transpose to [B,H,D,SEQP], 4 consecutive s per 8B store
      #pragma unroll
      for (int mf = 0; mf < 4; ++mf) {
        int mg0 = m0w + mf * 16 + lr * 4;
        int b = mg0 >> 11, s0 = mg0 & 2047;
        ushort4 pk;
        pk.x = f2bf(acc[mf][2 * pl][0] + b1);
        pk.y = f2bf(acc[mf][2 * pl][1] + b1);
        pk.z = f2bf(acc[mf][2 * pl][2] + b1);
        pk.w = f2bf(acc[mf][2 * pl][3] + b1);
        *(ushort4*)(vbt + ((size_t)(b * NH + h) * HD + d1) * SEQP + s0) = pk;
        pk.x = f2bf(acc[mf][2 * pl + 1][0] + b2);
        pk.y = f2bf(acc[mf][2 * pl + 1][1] + b2);
        pk.z = f2bf(acc[mf][2 * pl + 1][2] + b2);
        pk.w = f2bf(acc[mf][2 * pl + 1][3] + b2);
        *(ushort4*)(vbt + ((size_t)(b * NH + h) * HD + d1 + 64) * SEQP + s0) = pk;
      }
    } else {
      u16* basep = (w == 0) ? qb : kb;
      const float qs = (w == 0) ? 0.12751569843736827f : 1.0f;  // log2(e)/sqrt(128) into q
      #pragma unroll
      for (int mf = 0; mf < 4; ++mf)
        #pragma unroll
        for (int r = 0; r < 4; ++r) {
          int mg = m0w + mf * 16 + lr * 4 + r;
          int b = mg >> 11, s = mg & 2047;
          u16* dst = basep + ((size_t)(b * NH + h) * SEQ + s) * HD;
          float c1 = acc[mf][2 * pl][r]     + b1;
          float c2 = acc[mf][2 * pl + 1][r] + b2;
          float2 s1 = tab[s * HD + d1];
          float2 s2 = tab[s * HD + d1 + 64];
          dst[d1]      = f2bf((c1 * s1.x - c2 * s1.y) * qs);
          dst[d1 + 64] = f2bf((c2 * s2.x + c1 * s2.y) * qs);
        }
    }
  }
}

// ---------------- flash attention: QT=256, KT=64; R16 overlap + HW bf16 pack ----------------
// (R20 form, verified: no setprio in lockstep; softmax/PV split into two
// key-halves; P->bf16 pack via v_cvt_pk_bf16_f32. UNCHANGED.)
__global__ __launch_bounds__(512, 1) void k_flash(
    const u16* __restrict__ qb, const u16* __restrict__ kb,
    const u16* __restrict__ vbt, float* __restrict__ out)
{
  __shared__ __align__(16) u16 lsK[2][KT * HD];   // [key][d]  16 KB x2
  __shared__ __align__(16) u16 lsV[2][HD * KT];   // [d][key]  16 KB x2
  __shared__ __align__(16) u16 lsP[8][WQ * KT];   // per-wave [qrow][key], 4 KB x8

  const int tid = threadIdx.x;            // 0..511
  const int wave = tid >> 6, lane = tid & 63;
  const int lq = lane & 15, lr = lane >> 4;
  const int i = blockIdx.x;               // 0..255
  const int xcd = i & 7, j = i >> 3;      // j: 0..31
  const int bh = xcd * 4 + (j >> 3);      // 4 heads per XCD
  const int q0 = (j & 7) * QT;
  const u16* Qg = qb + ((size_t)bh * SEQ + q0 + wave * WQ) * HD;
  const u16* Kg = kb + (size_t)bh * SEQ * HD;
  const u16* Vg = vbt + (size_t)bh * HD * SEQP;

  auto stage = [&](int tile, int buf) {
    const int k0 = tile * KT;
    #pragma unroll
    for (int ii = 0; ii < 2; ++ii) {
      int c = tid + ii * 512;             // 0..1023 (16 KB K tile)
      int key = c >> 4, grp = c & 15;
      async16(Kg + (size_t)(k0 + key) * HD + ((grp ^ (key & 7)) * 8), lsK[buf] + c * 8);
    }
    #pragma unroll
    for (int ii = 0; ii < 2; ++ii) {
      int c = tid + ii * 512;             // 0..1023 (16 KB V tile)
      int d = c >> 3, g2 = c & 7;
      async16(Vg + (size_t)d * SEQP + k0 + ((g2 ^ ((d >> 1) & 7)) * 8), lsV[buf] + c * 8);
    }
  };

  stage(0, 0);

  bf16x8 qf[2][4];
  #pragma unroll
  for (int qq = 0; qq < 2; ++qq)
    #pragma unroll
    for (int ks = 0; ks < 4; ++ks)
      qf[qq][ks] = *(const bf16x8*)(Qg + (size_t)(qq * 16 + lq) * HD + ks * 32 + lr * 8);

  f32x4 acc_o[2][8];
  float lsum[2] = {0.f, 0.f};
  #pragma unroll
  for (int mb = 0; mb < 2; ++mb)
    #pragma unroll
    for (int nb = 0; nb < 8; ++nb) acc_o[mb][nb] = f32x4{0.f, 0.f, 0.f, 0.f};

  for (int t = 0; t < NTILE; ++t) {
    const int p = t & 1;
    __syncthreads();                 // drains stage(t); all waves done with buf 1-p
    if (t + 1 < NTILE) stage(t + 1, 1 - p);

    // S^T = K Q^T : 64 keys x 32 q-rows per wave
    f32x4 sacc[4][2];
    #pragma unroll
    for (int kbi = 0; kbi < 4; ++kbi)
      #pragma unroll
      for (int qq = 0; qq < 2; ++qq) sacc[kbi][qq] = f32x4{0.f, 0.f, 0.f, 0.f};
    #pragma unroll
    for (int ks = 0; ks < 4; ++ks) {
      bf16x8 kf[4];
      #pragma unroll
      for (int kbi = 0; kbi < 4; ++kbi) {
        int key = kbi * 16 + lq;
        int g = (ks * 4 + lr) ^ (key & 7);
        kf[kbi] = *(const bf16x8*)(lsK[p] + key * HD + g * 8);
      }
      #pragma unroll
      for (int kbi = 0; kbi < 4; ++kbi)
        #pragma unroll
        for (int qq = 0; qq < 2; ++qq)
          sacc[kbi][qq] = __builtin_amdgcn_mfma_f32_16x16x32_bf16(kf[kbi], qf[qq][ks], sacc[kbi][qq], 0, 0, 0);
    }

    // softmax + PV in two key-halves (overlap exp/pack of half 1 with PV of half 0)
    #pragma unroll
    for (int half = 0; half < 2; ++half) {
      // P = exp2(S) for kbi {2*half, 2*half+1}; HW-packed b64 writes
      #pragma unroll
      for (int kb2 = 0; kb2 < 2; ++kb2) {
        int kbi = half * 2 + kb2;
        #pragma unroll
        for (int qq = 0; qq < 2; ++qq) {
          float p0 = __builtin_amdgcn_exp2f(sacc[kbi][qq][0]);
          float p1 = __builtin_amdgcn_exp2f(sacc[kbi][qq][1]);
          float p2 = __builtin_amdgcn_exp2f(sacc[kbi][qq][2]);
          float p3 = __builtin_amdgcn_exp2f(sacc[kbi][qq][3]);
          lsum[qq] += (p0 + p1) + (p2 + p3);
          int row = qq * 16 + lq;
          int g = kbi * 4 + lr;                        // 0..15 (8B groups in 128B row)
          int gp = g ^ (row & 6) ^ ((row & 8) >> 1);
          uint2 pk;
          pk.x = cvtpk_bf16(p0, p1);
          pk.y = cvtpk_bf16(p2, p3);
          *(uint2*)(lsP[wave] + row * KT + gp * 4) = pk;
        }
      }

      // O += P V for this 32-key slot
      bf16x8 ap[2];
      #pragma unroll
      for (int mb = 0; mb < 2; ++mb) {
        int row = mb * 16 + lq;
        int sw = (row & 6) ^ ((row & 8) >> 1);
        int gb = (half * 8 + 2 * lr) ^ sw;             // even -> 16B-aligned
        ap[mb] = *(const bf16x8*)(lsP[wave] + row * KT + gb * 4);
      }
      #pragma unroll
      for (int nb = 0; nb < 8; ++nb) {
        int d = nb * 16 + lq;
        int q8 = (half * 4 + lr) ^ ((d >> 1) & 7);
        bf16x8 bv = *(const bf16x8*)(lsV[p] + d * KT + q8 * 8);
        #pragma unroll
        for (int mb = 0; mb < 2; ++mb)
          acc_o[mb][nb] = __builtin_amdgcn_mfma_f32_16x16x32_bf16(ap[mb], bv, acc_o[mb][nb], 0, 0, 0);
      }
    }
  }

  float inv[2];
  #pragma unroll
  for (int qq = 0; qq < 2; ++qq) {
    float s = lsum[qq];
    s += __shfl_xor(s, 16);
    s += __shfl_xor(s, 32);
    inv[qq] = 1.0f / s;
  }
  const int b = bh >> 4, h = bh & 15;
  #pragma unroll
  for (int mb = 0; mb < 2; ++mb)
    #pragma unroll
    for (int r = 0; r < 4; ++r) {
      float iv = __shfl(inv[mb], lr * 4 + r);
      int row = wave * WQ + mb * 16 + lr * 4 + r;
      int sq = q0 + row;
      float* op = out + (((size_t)b * SEQ + sq) * NH + h) * HD;
      #pragma unroll
      for (int nb = 0; nb < 8; ++nb)
        op[nb * 16 + lq] = acc_o[mb][nb][r] * iv;
    }
}

// ---------------- launch ----------------

extern "C" void kernel_launch(void* const* d_in, const int* in_sizes, int n_in,
                              void* d_out, int out_size, void* d_ws, size_t ws_size,
                              hipStream_t stream) {
  (void)in_sizes; (void)n_in; (void)out_size; (void)ws_size;
  const float* x    = (const float*)d_in[0];
  const float* W    = (const float*)d_in[1];
  const float* bias = (const float*)d_in[2];
  float* out = (float*)d_out;

  char* p = (char*)d_ws;
  u16* xb  = (u16*)p;  p += (size_t)MM * EMB * 2;                     // 16.8 MB
  u16* wt  = (u16*)p;  p += (size_t)N3 * EMB * 2;                     // 25.2 MB
  u16* qb  = (u16*)p;  p += (size_t)NUM_B * NH * SEQ * HD * 2;        // 16.8 MB
  u16* kb  = (u16*)p;  p += (size_t)NUM_B * NH * SEQ * HD * 2;        // 16.8 MB
  u16* vbt = (u16*)p;  p += (size_t)NUM_B * NH * HD * SEQP * 2;       // 17.0 MB
  float2* tab = (float2*)p;                                           // 2.1 MB

  k_prep<<<CVT_BLKS + TRN_BX * (EMB / 32), 256, 0, stream>>>(x, xb, tab, W, wt);
  k_gemm_qkv<<<dim3(N3 / BN, MM / BM), 512, 0, stream>>>(xb, wt, bias, tab, qb, kb, vbt);
  k_flash<<<SEQ / QT * NUM_B * NH, 512, 0, stream>>>(qb, kb, vbt, out);
}